// Round 5
// baseline (2424.268 us; speedup 1.0000x reference)
//
#include <hip/hip_runtime.h>

#define EPSF 1e-5f

typedef __attribute__((ext_vector_type(8))) short short8;
typedef __attribute__((ext_vector_type(4))) float f32x4;

__device__ __forceinline__ ushort f2bf(float x) {
    union { float f; unsigned u; } c; c.f = x;
    unsigned r = c.u + 0x7FFF + ((c.u >> 16) & 1);   // RNE
    return (ushort)(r >> 16);
}
__device__ __forceinline__ float bf2f(ushort b) {
    union { unsigned u; float f; } c; c.u = ((unsigned)b) << 16;
    return c.f;
}
// LDS swizzle: window stored as [pos][32ch] (64B per pos). Spread bits 4-6.
__device__ __forceinline__ int swz(int lin) {
    int sp = lin >> 6;
    return lin ^ ((((sp & 3) ^ ((sp >> 2) & 3)) << 4) | (((sp >> 1) & 1) << 6));
}

// ---------------------------------------------------------------------------
// Geometry: B=1, C=32, H=96, W=128, L=2, N=7 (49 displacements)
// Activations NHWC bf16, 1-px zero halo:
//   x0s [d][98][130][32] (sampled f2 only)   x1 [d][98][130][96]
//   x2,x3 [d][50][66][128]   x4 [d][50][66][64]   x5 [d][98][130][32]
// P1 [96][12288] f32 planar = f1 (x) W1[:, :32]  (d-independent part of conv1)
// Weights: [tap][COUT][CIN] bf16;  ctw5: [parity][tap][32][64]
// ---------------------------------------------------------------------------

__global__ __launch_bounds__(256) void k_repack_conv(
    const float* __restrict__ src, ushort* __restrict__ dst, int CO, int CI)
{
    int idx = blockIdx.x * 256 + threadIdx.x;
    if (idx >= CO * CI * 9) return;
    int co = idx / (CI * 9);
    int rem = idx % (CI * 9);
    int ci = rem / 9, tap = rem % 9;
    dst[((size_t)tap * CO + co) * CI + ci] = f2bf(src[idx]);
}

__global__ __launch_bounds__(256) void k_repack_ct(
    const float* __restrict__ src, ushort* __restrict__ dst)
{
    int idx = blockIdx.x * 256 + threadIdx.x;
    if (idx >= 4 * 4 * 32 * 64) return;
    int ci = idx & 63;
    int t = idx >> 6;
    int co = t & 31; t >>= 5;
    int tap = t & 3;
    int parity = t >> 2;
    int ph = parity >> 1, pw = parity & 1;
    int a = tap >> 1, b = tap & 1;
    int kh = ((ph + 1) & 1) + 2 * a;
    int kw = ((pw + 1) & 1) + 2 * b;
    dst[idx] = f2bf(src[((ci * 32 + co) * 4 + kh) * 4 + kw]);
}

__global__ __launch_bounds__(256) void k_zero_pads(
    ushort* __restrict__ buf, int PH, int PW, int CH)
{
    const int r = blockIdx.x, d = blockIdx.y;
    ushort* row = buf + ((size_t)d * PH + r) * PW * CH;
    if (r == 0 || r == PH - 1) {
        for (int i = threadIdx.x; i < PW * CH; i += 256) row[i] = 0;
    } else {
        for (int i = threadIdx.x; i < 2 * CH; i += 256) {
            int c = (i < CH) ? i : ((PW - 1) * CH + (i - CH));
            row[c] = 0;
        }
    }
}

// ---------------- pack f1 -> xf1 padded [98][130][32] ----------------------
__global__ __launch_bounds__(256) void k_pack_f1(
    const float* __restrict__ f1, ushort* __restrict__ xf1)
{
    const int sp = blockIdx.x * 256 + threadIdx.x;
    const int r = sp >> 7, c = sp & 127;
    ushort* dst = xf1 + ((size_t)(r + 1) * 130 + (c + 1)) * 32;
    #pragma unroll
    for (int g = 0; g < 4; ++g) {
        uint4 pk;
        uint* pw_ = (uint*)&pk;
        #pragma unroll
        for (int q = 0; q < 4; ++q) {
            int cc = g * 8 + q * 2;
            pw_[q] = (uint)f2bf(f1[(size_t)cc * 12288 + sp])
                   | ((uint)f2bf(f1[(size_t)(cc + 1) * 12288 + sp]) << 16);
        }
        *(uint4*)(dst + g * 8) = pk;
    }
}

// ---------------- sample f2 -> x0s padded [d][98][130][32] -----------------
__global__ __launch_bounds__(256) void k_sample_nhwc(
    const float* __restrict__ f2, const float* __restrict__ coords,
    ushort* __restrict__ x0s, int d0, float inv_scale)
{
    const int HW = 12288;
    const int sp = blockIdx.x * 256 + threadIdx.x;
    const int dd = blockIdx.z;
    const int d = d0 + dd;
    const int du = d / 7, dv = d % 7;

    float cx = coords[sp] * inv_scale + (float)(du - 3);
    float cy = coords[HW + sp] * inv_scale + (float)(dv - 3);
    float xf = floorf(cx), yf = floorf(cy);
    float wx = cx - xf, wy = cy - yf;
    int xi = (int)xf, yi = (int)yf;
    float vx0 = (xf >= 0.f && xf <= 127.f) ? 1.f : 0.f;
    float vx1 = (xf + 1.f >= 0.f && xf + 1.f <= 127.f) ? 1.f : 0.f;
    float vy0 = (yf >= 0.f && yf <= 95.f) ? 1.f : 0.f;
    float vy1 = (yf + 1.f >= 0.f && yf + 1.f <= 95.f) ? 1.f : 0.f;
    int x0i = min(max(xi, 0), 127), x1i = min(max(xi + 1, 0), 127);
    int y0i = min(max(yi, 0), 95),  y1i = min(max(yi + 1, 0), 95);
    float w00 = (1.f - wx) * (1.f - wy) * vx0 * vy0;
    float w01 = wx * (1.f - wy) * vx1 * vy0;
    float w10 = (1.f - wx) * wy * vx0 * vy1;
    float w11 = wx * wy * vx1 * vy1;
    int o00 = y0i * 128 + x0i, o01 = y0i * 128 + x1i;
    int o10 = y1i * 128 + x0i, o11 = y1i * 128 + x1i;

    const int r = sp >> 7, c = sp & 127;
    ushort* dst = x0s + ((size_t)dd * 98 * 130 + (size_t)(r + 1) * 130 + (c + 1)) * 32;
    #pragma unroll
    for (int g = 0; g < 4; ++g) {
        uint4 pk;
        uint* pw_ = (uint*)&pk;
        #pragma unroll
        for (int q = 0; q < 4; ++q) {
            uint wv = 0;
            #pragma unroll
            for (int h = 0; h < 2; ++h) {
                int cc = g * 8 + q * 2 + h;
                const float* fc = f2 + (size_t)cc * HW;
                float s = w00 * fc[o00] + w01 * fc[o01] + w10 * fc[o10] + w11 * fc[o11];
                wv |= ((uint)f2bf(s)) << (16 * h);
            }
            pw_[q] = wv;
        }
        *(uint4*)(dst + g * 8) = pk;
    }
}

// ---------------- generic stride-1 conv3x3, dbuf LDS window ----------------
// Block = 4 waves; tile = 4 out-rows x 64 out-cols; window 6x66 pos x 32ch.
// Phases = (d in chunk) x (32-ch K slices).  EPI: 0 = BN+ReLU padded bf16,
// 1 = raw f32 planar (P1).  IP1: init acc from f32 planar p1.
template <int CBUF, int WST, int CC, int COUT, int IH, int IW, int DCH,
          int EPI, bool IP1>
__global__ __launch_bounds__(256, 2) void k_conv_s1(
    const ushort* __restrict__ in, ushort* __restrict__ out,
    const ushort* __restrict__ w, int koff,
    const float* __restrict__ bs, const float* __restrict__ bb,
    const float* __restrict__ bm, const float* __restrict__ bv,
    const float* __restrict__ p1, int dc)
{
    constexpr int NF = COUT / 16;
    constexpr int IWP = IW + 2;
    constexpr int NCT = IW / 64;
    constexpr int WINB = 6 * 66 * 64;            // 25344 bytes
    constexpr int S = (WINB + 4095) / 4096;      // 7
    __shared__ char smem[2][WINB];

    const int tid = threadIdx.x;
    const int lane = tid & 63, wid = tid >> 6;
    const int lr = lane & 15, kg = lane >> 4;
    const int rt = (int)blockIdx.x / NCT, ct = (int)blockIdx.x % NCT;
    const int r0 = rt * 4, c0 = ct * 64;
    const int dd0 = (int)blockIdx.y * DCH;
    const int ndd = min(DCH, dc - dd0);
    const int NP = ndd * CC;

    int soff[S], sdst[S];
    bool smask[S];
    #pragma unroll
    for (int i = 0; i < S; ++i) {
        int lin = (i * 256 + tid) * 16;
        smask[i] = lin < WINB;
        int pos = lin >> 6;
        int row = (pos * 994) >> 16;             // pos/66 for pos<594
        int col = pos - row * 66;
        soff[i] = (row * IWP + col) * CBUF + ((lin & 63) >> 1);
        sdst[i] = swz(lin);
    }

    float binv[NF], bbeta[NF];
    if constexpr (EPI == 0) {
        #pragma unroll
        for (int nf = 0; nf < NF; ++nf) {
            int ch = nf * 16 + lr;
            float iv = bs[ch] * rsqrtf(bv[ch] + EPSF);
            binv[nf] = iv;
            bbeta[nf] = bb[ch] - bm[ch] * iv;
        }
    }

    f32x4 acc[4][NF];
    short8 stg[S];

    auto do_load = [&](int p) {
        int dd = dd0 + p / CC, cc = p % CC;
        const ushort* base = in + (((size_t)dd * (IH + 2) + r0) * IWP + c0) * CBUF + cc * 32;
        #pragma unroll
        for (int i = 0; i < S; ++i)
            if (smask[i]) stg[i] = *(const short8*)(base + soff[i]);
    };
    auto do_write = [&](int p) {
        char* buf = smem[p & 1];
        #pragma unroll
        for (int i = 0; i < S; ++i)
            if (smask[i]) *(short8*)(buf + sdst[i]) = stg[i];
    };

    do_load(0);
    do_write(0);
    __syncthreads();

    #pragma unroll 1
    for (int p = 0; p < NP; ++p) {
        const int dd = dd0 + p / CC, cc = p % CC;
        if (p + 1 < NP) do_load(p + 1);          // T14: issue early

        if (cc == 0) {
            if constexpr (IP1) {
                const int pbase = (r0 + wid) * IW + c0 + kg * 4;
                #pragma unroll
                for (int nf = 0; nf < NF; ++nf) {
                    const float* pp = p1 + (size_t)(nf * 16 + lr) * (IH * IW) + pbase;
                    #pragma unroll
                    for (int mf = 0; mf < 4; ++mf)
                        acc[mf][nf] = *(const f32x4*)(pp + mf * 16);
                }
            } else {
                #pragma unroll
                for (int mf = 0; mf < 4; ++mf)
                    #pragma unroll
                    for (int nf = 0; nf < NF; ++nf)
                        acc[mf][nf] = (f32x4){0.f, 0.f, 0.f, 0.f};
            }
        }

        const char* buf = smem[p & 1];
        const ushort* wt0 = w + koff + cc * 32;
        #pragma unroll
        for (int kh = 0; kh < 3; ++kh) {
            #pragma unroll
            for (int kw = 0; kw < 3; ++kw) {
                short8 a[4];
                #pragma unroll
                for (int mf = 0; mf < 4; ++mf) {
                    int sp = (wid + kh) * 66 + mf * 16 + lr + kw;
                    a[mf] = *(const short8*)(buf + swz(sp * 64 + kg * 16));
                }
                const ushort* wt = wt0 + (size_t)(kh * 3 + kw) * COUT * WST;
                #pragma unroll
                for (int nf = 0; nf < NF; ++nf) {
                    short8 bfr = *(const short8*)(wt + (size_t)(nf * 16 + lr) * WST + kg * 8);
                    #pragma unroll
                    for (int mf = 0; mf < 4; ++mf)
                        acc[mf][nf] = __builtin_amdgcn_mfma_f32_16x16x32_bf16(
                            a[mf], bfr, acc[mf][nf], 0, 0, 0);
                }
            }
        }

        if (cc == CC - 1) {
            if constexpr (EPI == 0) {
                ushort* ob = out + (size_t)dd * (IH + 2) * IWP * COUT;
                const size_t rowb = (size_t)(r0 + wid + 1) * IWP;
                #pragma unroll
                for (int nf = 0; nf < NF; ++nf) {
                    #pragma unroll
                    for (int mf = 0; mf < 4; ++mf) {
                        #pragma unroll
                        for (int j = 0; j < 4; ++j) {
                            int colp = c0 + mf * 16 + kg * 4 + j + 1;
                            float y = fmaxf(fmaf(acc[mf][nf][j], binv[nf], bbeta[nf]), 0.f);
                            ob[(rowb + colp) * COUT + nf * 16 + lr] = f2bf(y);
                        }
                    }
                }
            } else {
                float* of = (float*)out;         // raw planar f32 [COUT][IH*IW]
                const int pbase = (r0 + wid) * IW + c0 + kg * 4;
                #pragma unroll
                for (int nf = 0; nf < NF; ++nf) {
                    float* op = of + (size_t)(nf * 16 + lr) * (IH * IW) + pbase;
                    #pragma unroll
                    for (int mf = 0; mf < 4; ++mf)
                        *(f32x4*)(op + mf * 16) = acc[mf][nf];
                }
            }
        }

        if (p + 1 < NP) do_write(p + 1);
        __syncthreads();
    }
}

// ---------------- conv2: 3x3 stride-2, single-buf LDS window ---------------
// in x1 [98][130][96] -> out x2 [50][66][128].  tile 4x32 out, window 9x66x32.
template <int DCH>
__global__ __launch_bounds__(256, 2) void k_conv_s2(
    const ushort* __restrict__ in, ushort* __restrict__ out,
    const ushort* __restrict__ w,
    const float* __restrict__ bs, const float* __restrict__ bb,
    const float* __restrict__ bm, const float* __restrict__ bv, int dc)
{
    constexpr int WINB = 9 * 66 * 64;            // 38016
    constexpr int S = (WINB + 4095) / 4096;      // 10
    __shared__ char smem[WINB];

    const int tid = threadIdx.x;
    const int lane = tid & 63, wid = tid >> 6;
    const int lr = lane & 15, kg = lane >> 4;
    const int mh = wid >> 1, nh = wid & 1;
    const int rt = (int)blockIdx.x >> 1, ct = (int)blockIdx.x & 1;
    const int r0 = rt * 4, oc0 = ct * 32;
    const int dd0 = (int)blockIdx.y * DCH;
    const int ndd = min(DCH, dc - dd0);
    const int NP = ndd * 3;

    int soff[S], sdst[S];
    bool smask[S];
    #pragma unroll
    for (int i = 0; i < S; ++i) {
        int lin = (i * 256 + tid) * 16;
        smask[i] = lin < WINB;
        int pos = lin >> 6;
        int row = (pos * 994) >> 16;
        int col = pos - row * 66;
        soff[i] = (row * 130 + col) * 96 + ((lin & 63) >> 1);
        sdst[i] = swz(lin);
    }

    float binv[4], bbeta[4];
    #pragma unroll
    for (int n = 0; n < 4; ++n) {
        int ch = (nh * 4 + n) * 16 + lr;
        float iv = bs[ch] * rsqrtf(bv[ch] + EPSF);
        binv[n] = iv;
        bbeta[n] = bb[ch] - bm[ch] * iv;
    }

    f32x4 acc[4][4];
    short8 stg[S];

    auto do_load = [&](int p) {
        int dd = dd0 + p / 3, cc = p % 3;
        const ushort* base = in + (((size_t)dd * 98 + 2 * r0) * 130 + 2 * oc0) * 96 + cc * 32;
        #pragma unroll
        for (int i = 0; i < S; ++i)
            if (smask[i]) stg[i] = *(const short8*)(base + soff[i]);
    };
    auto do_write = [&]() {
        #pragma unroll
        for (int i = 0; i < S; ++i)
            if (smask[i]) *(short8*)(smem + sdst[i]) = stg[i];
    };

    do_load(0);
    do_write();
    __syncthreads();

    #pragma unroll 1
    for (int p = 0; p < NP; ++p) {
        const int dd = dd0 + p / 3, cc = p % 3;
        if (p + 1 < NP) do_load(p + 1);

        if (cc == 0) {
            #pragma unroll
            for (int i = 0; i < 4; ++i)
                #pragma unroll
                for (int n = 0; n < 4; ++n)
                    acc[i][n] = (f32x4){0.f, 0.f, 0.f, 0.f};
        }

        const ushort* wt0 = w + cc * 32;
        #pragma unroll
        for (int kh = 0; kh < 3; ++kh) {
            #pragma unroll
            for (int kw = 0; kw < 3; ++kw) {
                short8 a[4];
                #pragma unroll
                for (int i = 0; i < 4; ++i) {
                    int wrow = 2 * (mh * 2 + (i >> 1)) + kh;
                    int wcol = 2 * ((i & 1) * 16 + lr) + kw;
                    int sp = wrow * 66 + wcol;
                    a[i] = *(const short8*)(smem + swz(sp * 64 + kg * 16));
                }
                const ushort* wt = wt0 + (size_t)(kh * 3 + kw) * 128 * 96;
                #pragma unroll
                for (int n = 0; n < 4; ++n) {
                    short8 bfr = *(const short8*)(wt + (size_t)((nh * 4 + n) * 16 + lr) * 96 + kg * 8);
                    #pragma unroll
                    for (int i = 0; i < 4; ++i)
                        acc[i][n] = __builtin_amdgcn_mfma_f32_16x16x32_bf16(
                            a[i], bfr, acc[i][n], 0, 0, 0);
                }
            }
        }

        if (cc == 2) {
            ushort* ob = out + (size_t)dd * 50 * 66 * 128;
            #pragma unroll
            for (int n = 0; n < 4; ++n) {
                #pragma unroll
                for (int i = 0; i < 4; ++i) {
                    int row = r0 + mh * 2 + (i >> 1) + 1;
                    #pragma unroll
                    for (int j = 0; j < 4; ++j) {
                        int col = oc0 + (i & 1) * 16 + kg * 4 + j + 1;
                        float y = fmaxf(fmaf(acc[i][n][j], binv[n], bbeta[n]), 0.f);
                        ob[((size_t)row * 66 + col) * 128 + (nh * 4 + n) * 16 + lr] = f2bf(y);
                    }
                }
            }
        }
        __syncthreads();
        if (p + 1 < NP) do_write();
        __syncthreads();
    }
}

// ---------------- convT 4x4 s2, dbuf window, 4 parities per block ----------
// in x4 [50][66][64] -> out x5 [98][130][32].  w [parity][tap][32][64].
template <int DCH>
__global__ __launch_bounds__(256, 2) void k_convt(
    const ushort* __restrict__ in, ushort* __restrict__ out,
    const ushort* __restrict__ w,
    const float* __restrict__ bs, const float* __restrict__ bb,
    const float* __restrict__ bm, const float* __restrict__ bv, int dc)
{
    constexpr int WINB = 6 * 66 * 64;
    constexpr int S = (WINB + 4095) / 4096;
    __shared__ char smem[2][WINB];

    const int tid = threadIdx.x;
    const int lane = tid & 63, wid = tid >> 6;
    const int lr = lane & 15, kg = lane >> 4;
    const int q0 = (int)blockIdx.x * 4;
    const int dd0 = (int)blockIdx.y * DCH;
    const int ndd = min(DCH, dc - dd0);
    const int NP = ndd * 2;

    int soff[S], sdst[S];
    bool smask[S];
    #pragma unroll
    for (int i = 0; i < S; ++i) {
        int lin = (i * 256 + tid) * 16;
        smask[i] = lin < WINB;
        int pos = lin >> 6;
        int row = (pos * 994) >> 16;
        int col = pos - row * 66;
        soff[i] = (row * 66 + col) * 64 + ((lin & 63) >> 1);
        sdst[i] = swz(lin);
    }

    float binv[2], bbeta[2];
    #pragma unroll
    for (int nf = 0; nf < 2; ++nf) {
        int ch = nf * 16 + lr;
        float iv = bs[ch] * rsqrtf(bv[ch] + EPSF);
        binv[nf] = iv;
        bbeta[nf] = bb[ch] - bm[ch] * iv;
    }

    f32x4 acc[4][4][2];   // [parity][mf][nf]
    short8 stg[S];

    auto do_load = [&](int p) {
        int dd = dd0 + (p >> 1), cc = p & 1;
        const ushort* base = in + ((size_t)dd * 50 + q0) * 66 * 64 + cc * 32;
        #pragma unroll
        for (int i = 0; i < S; ++i)
            if (smask[i]) stg[i] = *(const short8*)(base + soff[i]);
    };
    auto do_write = [&](int p) {
        char* buf = smem[p & 1];
        #pragma unroll
        for (int i = 0; i < S; ++i)
            if (smask[i]) *(short8*)(buf + sdst[i]) = stg[i];
    };

    do_load(0);
    do_write(0);
    __syncthreads();

    // per shift (sr,sc): list of (ph, a) with ph+1-a == sr  (same for cols)
    constexpr int NPAIR[3] = {1, 2, 1};
    constexpr int PHT[3][2] = {{0, 0}, {0, 1}, {1, 0}};
    constexpr int AAT[3][2] = {{1, 0}, {0, 1}, {0, 0}};

    #pragma unroll 1
    for (int p = 0; p < NP; ++p) {
        const int dd = dd0 + (p >> 1), cc = p & 1;
        if (p + 1 < NP) do_load(p + 1);

        if (cc == 0) {
            #pragma unroll
            for (int pa = 0; pa < 4; ++pa)
                #pragma unroll
                for (int mf = 0; mf < 4; ++mf)
                    #pragma unroll
                    for (int nf = 0; nf < 2; ++nf)
                        acc[pa][mf][nf] = (f32x4){0.f, 0.f, 0.f, 0.f};
        }

        const char* buf = smem[p & 1];
        #pragma unroll
        for (int sr = 0; sr < 3; ++sr) {
            #pragma unroll
            for (int sc = 0; sc < 3; ++sc) {
                short8 a[4];
                #pragma unroll
                for (int mf = 0; mf < 4; ++mf) {
                    int sp = (wid + sr) * 66 + mf * 16 + lr + sc;
                    a[mf] = *(const short8*)(buf + swz(sp * 64 + kg * 16));
                }
                #pragma unroll
                for (int t1 = 0; t1 < NPAIR[sr]; ++t1) {
                    #pragma unroll
                    for (int t2 = 0; t2 < NPAIR[sc]; ++t2) {
                        const int ph = PHT[sr][t1], aa = AAT[sr][t1];
                        const int pw = PHT[sc][t2], bb2 = AAT[sc][t2];
                        const int par = ph * 2 + pw, tap = aa * 2 + bb2;
                        const ushort* wt = w + (size_t)(par * 4 + tap) * 32 * 64 + cc * 32;
                        #pragma unroll
                        for (int nf = 0; nf < 2; ++nf) {
                            short8 bfr = *(const short8*)(wt + (size_t)(nf * 16 + lr) * 64 + kg * 8);
                            #pragma unroll
                            for (int mf = 0; mf < 4; ++mf)
                                acc[par][mf][nf] = __builtin_amdgcn_mfma_f32_16x16x32_bf16(
                                    a[mf], bfr, acc[par][mf][nf], 0, 0, 0);
                        }
                    }
                }
            }
        }

        if (cc == 1) {
            ushort* ob = out + (size_t)dd * 98 * 130 * 32;
            #pragma unroll
            for (int pa = 0; pa < 4; ++pa) {
                const int ph = pa >> 1, pw = pa & 1;
                const size_t rowb = (size_t)(2 * (q0 + wid) + ph + 1) * 130;
                #pragma unroll
                for (int nf = 0; nf < 2; ++nf) {
                    #pragma unroll
                    for (int mf = 0; mf < 4; ++mf) {
                        #pragma unroll
                        for (int j = 0; j < 4; ++j) {
                            int ocol = 2 * (mf * 16 + kg * 4 + j) + pw + 1;
                            float y = fmaxf(fmaf(acc[pa][mf][nf][j], binv[nf], bbeta[nf]), 0.f);
                            ob[(rowb + ocol) * 32 + nf * 16 + lr] = f2bf(y);
                        }
                    }
                }
            }
        }

        if (p + 1 < NP) do_write(p + 1);
        __syncthreads();
    }
}

// ---------------- conv6 (32->1) + bias, padded in, fp32 out ----------------
__global__ __launch_bounds__(256) void k_conv6(
    const ushort* __restrict__ x5, float* __restrict__ cost,
    const float* __restrict__ w, const float* __restrict__ biasp, int d0)
{
    const int sp = blockIdx.x * 256 + threadIdx.x;
    const int dd = blockIdx.z;
    const int oh = sp >> 7, ow = sp & 127;
    float acc = 0.f;
    #pragma unroll
    for (int kh = 0; kh < 3; ++kh) {
        #pragma unroll
        for (int kw = 0; kw < 3; ++kw) {
            const ushort* p = x5 + ((size_t)dd * 98 * 130
                                  + (size_t)(oh + kh) * 130 + (ow + kw)) * 32;
            const int tap = kh * 3 + kw;
            #pragma unroll
            for (int q = 0; q < 4; ++q) {
                uint4 v = *(const uint4*)(p + q * 8);
                const uint* vw = (const uint*)&v;
                #pragma unroll
                for (int t = 0; t < 4; ++t) {
                    int ci = q * 8 + t * 2;
                    acc = fmaf(bf2f((ushort)(vw[t] & 0xFFFF)), w[ci * 9 + tap], acc);
                    acc = fmaf(bf2f((ushort)(vw[t] >> 16)), w[(ci + 1) * 9 + tap], acc);
                }
            }
        }
    }
    cost[(size_t)(d0 + dd) * 12288 + sp] = acc + biasp[0];
}

// ---------------- DAP ------------------------------------------------------
__global__ __launch_bounds__(256) void k_dap(
    const float* __restrict__ cost, const float* __restrict__ dw,
    float* __restrict__ out)
{
    const int sp = blockIdx.x * 256 + threadIdx.x;
    const int p = blockIdx.y;
    const float* dr = dw + p * 49;
    float acc = 0.f;
    #pragma unroll
    for (int q = 0; q < 49; ++q)
        acc = fmaf(dr[q], cost[(size_t)q * 12288 + sp], acc);
    out[(size_t)p * 12288 + sp] = acc;
}

// ---------------------------------------------------------------------------
extern "C" void kernel_launch(void* const* d_in, const int* in_sizes, int n_in,
                              void* d_out, int out_size, void* d_ws, size_t ws_size,
                              hipStream_t stream)
{
    const float* fm1[2] = { (const float*)d_in[0], (const float*)d_in[2] };
    const float* fm2[2] = { (const float*)d_in[1], (const float*)d_in[3] };
    const float* coords = (const float*)d_in[4];
    const float* cw1  = (const float*)d_in[5];
    const float* cw2  = (const float*)d_in[6];
    const float* cw3  = (const float*)d_in[7];
    const float* cw4  = (const float*)d_in[8];
    const float* ctw5 = (const float*)d_in[9];
    const float* cw6  = (const float*)d_in[10];
    const float* cb6  = (const float*)d_in[11];
    const float* bn[5][4];
    for (int j = 0; j < 5; ++j)
        for (int k = 0; k < 4; ++k)
            bn[j][k] = (const float*)d_in[12 + j * 4 + k];
    const float* dap = (const float*)d_in[32];
    float* out = (float*)d_out;

    // ---- workspace sizes (ushort counts) ----
    const size_t X0S = (size_t)98 * 130 * 32;
    const size_t X1  = (size_t)98 * 130 * 96;
    const size_t X2  = (size_t)50 * 66 * 128;
    const size_t X3  = (size_t)50 * 66 * 128;
    const size_t X4  = (size_t)50 * 66 * 64;
    const size_t X5  = (size_t)98 * 130 * 32;
    const size_t PERD = X0S + X1 + X2 + X3 + X4 + X5;
    const size_t XF1 = (size_t)98 * 130 * 32;
    const size_t W_US = 2 * (size_t)(9*96*64 + 9*128*96 + 9*128*128 + 9*64*128 + 16*32*64);
    const size_t P1F = (size_t)96 * 12288;           // floats
    const size_t COSTF = (size_t)49 * 12288;         // floats

    int DC = 1;
    for (int cand : {49, 25, 17, 13, 9, 7, 5, 3, 2, 1}) {
        size_t need = (PERD * (size_t)cand + XF1 + W_US) * 2
                    + (P1F + COSTF) * 4 + 65536;
        if (need <= ws_size) { DC = cand; break; }
    }

    ushort* x0s = (ushort*)d_ws;
    ushort* x1 = x0s + X0S * DC;
    ushort* x2 = x1 + X1 * DC;
    ushort* x3 = x2 + X2 * DC;
    ushort* x4 = x3 + X3 * DC;
    ushort* x5 = x4 + X4 * DC;
    ushort* xf1 = x5 + X5 * DC;
    ushort* wp = xf1 + XF1;
    ushort* wr1[2], *wr2[2], *wr3[2], *wr4[2], *wr5[2];
    for (int l = 0; l < 2; ++l) {
        wr1[l] = wp; wp += 9 * 96 * 64;
        wr2[l] = wp; wp += 9 * 128 * 96;
        wr3[l] = wp; wp += 9 * 128 * 128;
        wr4[l] = wp; wp += 9 * 64 * 128;
        wr5[l] = wp; wp += 16 * 32 * 64;
    }
    float* P1 = (float*)wp;
    float* cost = P1 + P1F;

    // ---- weight repack ----
    for (int l = 0; l < 2; ++l) {
        k_repack_conv<<<dim3(216), 256, 0, stream>>>(cw1 + (size_t)l * 96 * 64 * 9,   wr1[l], 96, 64);
        k_repack_conv<<<dim3(432), 256, 0, stream>>>(cw2 + (size_t)l * 128 * 96 * 9,  wr2[l], 128, 96);
        k_repack_conv<<<dim3(576), 256, 0, stream>>>(cw3 + (size_t)l * 128 * 128 * 9, wr3[l], 128, 128);
        k_repack_conv<<<dim3(288), 256, 0, stream>>>(cw4 + (size_t)l * 64 * 128 * 9,  wr4[l], 64, 128);
        k_repack_ct<<<dim3(128), 256, 0, stream>>>(ctw5 + (size_t)l * 64 * 32 * 16, wr5[l]);
    }

    // ---- zero halos (interiors rewritten every chunk) ----
    k_zero_pads<<<dim3(98, 1),  256, 0, stream>>>(xf1, 98, 130, 32);
    k_zero_pads<<<dim3(98, DC), 256, 0, stream>>>(x0s, 98, 130, 32);
    k_zero_pads<<<dim3(98, DC), 256, 0, stream>>>(x1, 98, 130, 96);
    k_zero_pads<<<dim3(50, DC), 256, 0, stream>>>(x2, 50, 66, 128);
    k_zero_pads<<<dim3(50, DC), 256, 0, stream>>>(x3, 50, 66, 128);
    k_zero_pads<<<dim3(50, DC), 256, 0, stream>>>(x4, 50, 66, 64);
    k_zero_pads<<<dim3(98, DC), 256, 0, stream>>>(x5, 98, 130, 32);

    for (int l = 0; l < 2; ++l) {
        const float inv_scale = l ? 0.5f : 1.0f;
        // d-independent conv1 part: P1 = f1 (x) W1[:, 0:32]  (f32 planar)
        k_pack_f1<<<dim3(48), 256, 0, stream>>>(fm1[l], xf1);
        k_conv_s1<32, 64, 1, 96, 96, 128, 1, 1, false>
            <<<dim3(48, 1), 256, 0, stream>>>(xf1, (ushort*)P1, wr1[l], 0,
                bn[0][0], bn[0][1], bn[0][2], bn[0][3], nullptr, 1);

        for (int d0 = 0; d0 < 49; d0 += DC) {
            const int dc = min(DC, 49 - d0);
            k_sample_nhwc<<<dim3(48, 1, dc), 256, 0, stream>>>(
                fm2[l], coords, x0s, d0, inv_scale);
            k_conv_s1<32, 64, 1, 96, 96, 128, 4, 0, true>
                <<<dim3(48, (dc + 3) / 4), 256, 0, stream>>>(x0s, x1, wr1[l], 32,
                    bn[0][0] + l * 96,  bn[0][1] + l * 96,  bn[0][2] + l * 96,  bn[0][3] + l * 96,
                    P1, dc);
            k_conv_s2<3><<<dim3(24, (dc + 2) / 3), 256, 0, stream>>>(x1, x2, wr2[l],
                    bn[1][0] + l * 128, bn[1][1] + l * 128, bn[1][2] + l * 128, bn[1][3] + l * 128, dc);
            k_conv_s1<128, 128, 4, 128, 48, 64, 1, 0, false>
                <<<dim3(12, dc), 256, 0, stream>>>(x2, x3, wr3[l], 0,
                    bn[2][0] + l * 128, bn[2][1] + l * 128, bn[2][2] + l * 128, bn[2][3] + l * 128,
                    nullptr, dc);
            k_conv_s1<128, 128, 4, 64, 48, 64, 1, 0, false>
                <<<dim3(12, dc), 256, 0, stream>>>(x3, x4, wr4[l], 0,
                    bn[3][0] + l * 64,  bn[3][1] + l * 64,  bn[3][2] + l * 64,  bn[3][3] + l * 64,
                    nullptr, dc);
            k_convt<2><<<dim3(12, (dc + 1) / 2), 256, 0, stream>>>(x4, x5, wr5[l],
                    bn[4][0] + l * 32,  bn[4][1] + l * 32,  bn[4][2] + l * 32,  bn[4][3] + l * 32, dc);
            k_conv6<<<dim3(48, 1, dc), 256, 0, stream>>>(
                x5, cost, cw6 + (size_t)l * 32 * 9, cb6 + l, d0);
        }
        k_dap<<<dim3(48, 49), 256, 0, stream>>>(
            cost, dap + (size_t)l * 49 * 49, out + (size_t)l * 49 * 12288);
    }
}

// Round 6
// 1294.394 us; speedup vs baseline: 1.8729x; 1.8729x over previous
//
#include <hip/hip_runtime.h>

#define EPSF 1e-5f

typedef __attribute__((ext_vector_type(8))) short short8;
typedef __attribute__((ext_vector_type(4))) float f32x4;

__device__ __forceinline__ ushort f2bf(float x) {
    union { float f; unsigned u; } c; c.f = x;
    unsigned r = c.u + 0x7FFF + ((c.u >> 16) & 1);   // RNE
    return (ushort)(r >> 16);
}
__device__ __forceinline__ float bf2f(ushort b) {
    union { unsigned u; float f; } c; c.u = ((unsigned)b) << 16;
    return c.f;
}

// ---------------------------------------------------------------------------
// Geometry: B=1, C=32, H=96, W=128, L=2, N=7 (49 displacements/level).
// blockIdx.z spans merged (level,d) pairs p = d0 + z, p in [0,98).
// Activations NHWC bf16, unpadded, tensor-packed per slot (round-3 layout):
//   x0 [slot][12288][64]  x1 [slot][12288][96]  x2,x3 [slot][3072][128]
//   x4 [slot][3072][64]   x5 [slot][12288][32]
// Weights repacked [l][tap][COUT][CIN] bf16 (grouped per layer, stride wlstride)
// ---------------------------------------------------------------------------

__global__ __launch_bounds__(256) void k_repack_conv(
    const float* __restrict__ src, ushort* __restrict__ dst, int CO, int CI)
{
    int idx = blockIdx.x * 256 + threadIdx.x;
    if (idx >= CO * CI * 9) return;
    int co = idx / (CI * 9);
    int rem = idx % (CI * 9);
    int ci = rem / 9, tap = rem % 9;
    dst[((size_t)tap * CO + co) * CI + ci] = f2bf(src[idx]);
}

// ctw5 [64][32][4][4] fp32 -> [parity(4)][tap(4)][32co][64ci] bf16
__global__ __launch_bounds__(256) void k_repack_ct(
    const float* __restrict__ src, ushort* __restrict__ dst)
{
    int idx = blockIdx.x * 256 + threadIdx.x;
    if (idx >= 4 * 4 * 32 * 64) return;
    int ci = idx & 63;
    int t = idx >> 6;
    int co = t & 31; t >>= 5;
    int tap = t & 3;
    int parity = t >> 2;
    int ph = parity >> 1, pw = parity & 1;
    int a = tap >> 1, b = tap & 1;
    int kh = ((ph + 1) & 1) + 2 * a;
    int kw = ((pw + 1) & 1) + 2 * b;
    dst[idx] = f2bf(src[((ci * 32 + co) * 4 + kh) * 4 + kw]);
}

// ---------------- sample + concat -> x0 [slot][12288][64] ------------------
__global__ __launch_bounds__(256) void k_sample_nhwc(
    const float* __restrict__ f1_0, const float* __restrict__ f1_1,
    const float* __restrict__ f2_0, const float* __restrict__ f2_1,
    const float* __restrict__ coords, ushort* __restrict__ x0, int d0)
{
    const int HW = 12288;
    const int sp = blockIdx.x * 256 + threadIdx.x;
    const int slot = blockIdx.z;
    const int p = d0 + slot;
    const int l = p / 49;
    const int d = p - l * 49;
    const int du = d / 7, dv = d % 7;
    const float inv_scale = l ? 0.5f : 1.0f;
    const float* f1 = l ? f1_1 : f1_0;
    const float* f2 = l ? f2_1 : f2_0;

    float cx = coords[sp] * inv_scale + (float)(du - 3);
    float cy = coords[HW + sp] * inv_scale + (float)(dv - 3);
    float xf = floorf(cx), yf = floorf(cy);
    float wx = cx - xf, wy = cy - yf;
    int xi = (int)xf, yi = (int)yf;
    float vx0 = (xf >= 0.f && xf <= 127.f) ? 1.f : 0.f;
    float vx1 = (xf + 1.f >= 0.f && xf + 1.f <= 127.f) ? 1.f : 0.f;
    float vy0 = (yf >= 0.f && yf <= 95.f) ? 1.f : 0.f;
    float vy1 = (yf + 1.f >= 0.f && yf + 1.f <= 95.f) ? 1.f : 0.f;
    int x0i = min(max(xi, 0), 127), x1i = min(max(xi + 1, 0), 127);
    int y0i = min(max(yi, 0), 95),  y1i = min(max(yi + 1, 0), 95);
    float w00 = (1.f - wx) * (1.f - wy) * vx0 * vy0;
    float w01 = wx * (1.f - wy) * vx1 * vy0;
    float w10 = (1.f - wx) * wy * vx0 * vy1;
    float w11 = wx * wy * vx1 * vy1;
    int o00 = y0i * 128 + x0i, o01 = y0i * 128 + x1i;
    int o10 = y1i * 128 + x0i, o11 = y1i * 128 + x1i;

    ushort* dst = x0 + ((size_t)slot * HW + sp) * 64;
    #pragma unroll
    for (int g = 0; g < 4; ++g) {               // f1 channels 0..31
        uint4 pk;
        uint* pw_ = (uint*)&pk;
        #pragma unroll
        for (int q = 0; q < 4; ++q) {
            int c = g * 8 + q * 2;
            pw_[q] = (uint)f2bf(f1[(size_t)c * HW + sp])
                   | ((uint)f2bf(f1[(size_t)(c + 1) * HW + sp]) << 16);
        }
        *(uint4*)(dst + g * 8) = pk;
    }
    #pragma unroll
    for (int g = 0; g < 4; ++g) {               // sampled f2 channels 32..63
        uint4 pk;
        uint* pw_ = (uint*)&pk;
        #pragma unroll
        for (int q = 0; q < 4; ++q) {
            uint wv = 0;
            #pragma unroll
            for (int h = 0; h < 2; ++h) {
                int c = g * 8 + q * 2 + h;
                const float* fc = f2 + (size_t)c * HW;
                float s = w00 * fc[o00] + w01 * fc[o01] + w10 * fc[o10] + w11 * fc[o11];
                wv |= ((uint)f2bf(s)) << (16 * h);
            }
            pw_[q] = wv;
        }
        *(uint4*)(dst + 32 + g * 8) = pk;
    }
}

// ---------------- MFMA conv3x3 (+BN+ReLU), B-weights via LDS ---------------
// 4 waves; wave tile = 64 m-positions x (NFT*16) out-channels.
// blockIdx.y = COUT split (co0 = y*NFT*16).  K in 32-ch phases; weight slice
// [9][ROWS][32ch] staged in LDS (XOR-swizzled), next slice prefetched to regs.
template <int CIN, int COUT, int NFT, int STRIDE, int IH, int IW, int OH, int OW>
__global__ __launch_bounds__(256) void k_conv_mfma(
    const ushort* __restrict__ in, ushort* __restrict__ out,
    const ushort* __restrict__ wbase, int wlstride,
    const float* __restrict__ bs0, const float* __restrict__ bb0,
    const float* __restrict__ bm0, const float* __restrict__ bv0, int d0)
{
    constexpr int CC = CIN / 32;
    constexpr int ROWS = NFT * 16;
    constexpr int SLICE = 9 * ROWS * 64;          // bytes
    constexpr int S = (SLICE + 4095) / 4096;
    constexpr int OWS = (OW == 128) ? 7 : 6;
    __shared__ __align__(16) char smem[SLICE];

    const int tid = threadIdx.x;
    const int lane = tid & 63, wid = tid >> 6;
    const int lr = lane & 15, kg = lane >> 4;
    const int m0 = blockIdx.x * 256 + wid * 64;
    const int co0 = blockIdx.y * ROWS;
    const int slot = blockIdx.z;
    const int l = (d0 + slot) / 49;

    // staging address precompute (per-thread, once)
    int soff[S], sdst[S];
    bool smask[S];
    #pragma unroll
    for (int i = 0; i < S; ++i) {
        int lin = i * 4096 + tid * 16;
        smask[i] = lin < SLICE;
        int rowidx = lin >> 6;
        int tap = rowidx / ROWS;
        int r = rowidx - tap * ROWS;
        soff[i] = (tap * COUT + r) * (CIN * 2) + (lin & 63);
        sdst[i] = lin ^ ((rowidx & 3) << 4);
    }
    const char* wsrc = (const char*)(wbase + (size_t)l * wlstride)
                     + (size_t)co0 * (CIN * 2);

    int bh[4], bw[4];
    #pragma unroll
    for (int mf = 0; mf < 4; ++mf) {
        int m = m0 + mf * 16 + lr;
        bh[mf] = (m >> OWS) * STRIDE - 1;
        bw[mf] = (m & (OW - 1)) * STRIDE - 1;
    }
    const ushort* ib = in + (size_t)slot * IH * IW * CIN;
    const int bloff = lr * 64 + ((kg * 16) ^ ((lr & 3) << 4));

    const short8 z8 = {0, 0, 0, 0, 0, 0, 0, 0};
    f32x4 acc[4][NFT];
    #pragma unroll
    for (int mf = 0; mf < 4; ++mf)
        #pragma unroll
        for (int nf = 0; nf < NFT; ++nf)
            acc[mf][nf] = (f32x4){0.f, 0.f, 0.f, 0.f};

    short8 stg[S];
    #pragma unroll
    for (int i = 0; i < S; ++i)
        if (smask[i]) stg[i] = *(const short8*)(wsrc + soff[i]);

    #pragma unroll
    for (int cc = 0; cc < CC; ++cc) {
        if (cc) __syncthreads();                  // smem free for overwrite
        #pragma unroll
        for (int i = 0; i < S; ++i)
            if (smask[i]) *(short8*)(smem + sdst[i]) = stg[i];
        __syncthreads();
        if (cc + 1 < CC) {                        // T14: issue next slice early
            #pragma unroll
            for (int i = 0; i < S; ++i)
                if (smask[i]) stg[i] = *(const short8*)(wsrc + (cc + 1) * 64 + soff[i]);
        }
        const int kbase = cc * 32 + kg * 8;
        #pragma unroll
        for (int kh = 0; kh < 3; ++kh) {
            #pragma unroll
            for (int kw = 0; kw < 3; ++kw) {
                short8 a[4];
                #pragma unroll
                for (int mf = 0; mf < 4; ++mf) {
                    int ih = bh[mf] + kh, iw = bw[mf] + kw;
                    bool v = ((unsigned)ih < (unsigned)IH) && ((unsigned)iw < (unsigned)IW);
                    int ihc = min(max(ih, 0), IH - 1);
                    int iwc = min(max(iw, 0), IW - 1);
                    short8 t = *(const short8*)(ib + (ihc * IW + iwc) * CIN + kbase);
                    a[mf] = v ? t : z8;
                }
                const int tb = (kh * 3 + kw) * (ROWS * 64);
                #pragma unroll
                for (int nf = 0; nf < NFT; ++nf) {
                    short8 b = *(const short8*)(smem + tb + nf * 1024 + bloff);
                    #pragma unroll
                    for (int mf = 0; mf < 4; ++mf)
                        acc[mf][nf] = __builtin_amdgcn_mfma_f32_16x16x32_bf16(
                            a[mf], b, acc[mf][nf], 0, 0, 0);
                }
            }
        }
    }

    const float* bs = bs0 + l * COUT;
    const float* bb = bb0 + l * COUT;
    const float* bm = bm0 + l * COUT;
    const float* bv = bv0 + l * COUT;
    ushort* ob = out + (size_t)slot * OH * OW * COUT;
    #pragma unroll
    for (int nf = 0; nf < NFT; ++nf) {
        const int col = co0 + nf * 16 + lr;
        const float inv = bs[col] * rsqrtf(bv[col] + EPSF);
        const float beta = bb[col] - bm[col] * inv;
        #pragma unroll
        for (int mf = 0; mf < 4; ++mf) {
            #pragma unroll
            for (int j = 0; j < 4; ++j) {
                int row = m0 + mf * 16 + kg * 4 + j;
                float y = fmaxf(fmaf(acc[mf][nf][j], inv, beta), 0.f);
                ob[(size_t)row * COUT + col] = f2bf(y);
            }
        }
    }
}

// ---------------- MFMA convT4x4 s2 (+BN+ReLU), weights via LDS -------------
// in [slot][3072][64] -> out [slot][12288][32]; w [l][parity][tap][32][64]
__global__ __launch_bounds__(256) void k_convt_mfma(
    const ushort* __restrict__ in, ushort* __restrict__ out,
    const ushort* __restrict__ wbase,
    const float* __restrict__ bs0, const float* __restrict__ bb0,
    const float* __restrict__ bm0, const float* __restrict__ bv0, int d0)
{
    constexpr int SLICE = 4 * 32 * 128;           // 16384 bytes (one parity)
    constexpr int S = 4;
    __shared__ __align__(16) char smem[SLICE];

    const int tid = threadIdx.x;
    const int lane = tid & 63, wid = tid >> 6;
    const int lr = lane & 15, kg = lane >> 4;
    const int m0 = blockIdx.x * 256 + wid * 64;
    const int parity = blockIdx.y;
    const int slot = blockIdx.z;
    const int l = (d0 + slot) / 49;
    const int ph = parity >> 1, pw = parity & 1;
    const int kh0 = (ph + 1) & 1, kw0 = (pw + 1) & 1;

    // stage this parity's weights once: rows = tap*32+r, 128 B each
    {
        const char* wsrc = (const char*)(wbase + (size_t)l * (16 * 32 * 64));
        #pragma unroll
        for (int i = 0; i < S; ++i) {
            int lin = i * 4096 + tid * 16;
            int rowidx = lin >> 7;                // 0..127
            int tap = rowidx >> 5, r = rowidx & 31;
            short8 v = *(const short8*)(wsrc
                + (((size_t)(parity * 4 + tap) * 32 + r) * 64) * 2 + (lin & 127));
            *(short8*)(smem + (lin ^ ((rowidx & 3) << 4))) = v;
        }
    }
    __syncthreads();

    int ihA[4], iwA[4];
    #pragma unroll
    for (int mf = 0; mf < 4; ++mf) {
        int m = m0 + mf * 16 + lr;
        int q = m >> 6, r = m & 63;
        ihA[mf] = (2 * q + ph + 1 - kh0) >> 1;
        iwA[mf] = (2 * r + pw + 1 - kw0) >> 1;
    }
    const ushort* ib = in + (size_t)slot * 3072 * 64;
    const int bloff = lr * 128 + ((kg * 16) ^ ((lr & 3) << 4));

    const short8 z8 = {0, 0, 0, 0, 0, 0, 0, 0};
    f32x4 acc[4][2];
    #pragma unroll
    for (int mf = 0; mf < 4; ++mf)
        #pragma unroll
        for (int nf = 0; nf < 2; ++nf)
            acc[mf][nf] = (f32x4){0.f, 0.f, 0.f, 0.f};

    #pragma unroll
    for (int a = 0; a < 2; ++a) {
        #pragma unroll
        for (int b2 = 0; b2 < 2; ++b2) {
            int srcoff[4]; bool val[4];
            #pragma unroll
            for (int mf = 0; mf < 4; ++mf) {
                int ih = ihA[mf] - a;
                int iw = iwA[mf] - b2;
                val[mf] = ((unsigned)ih < 48u) && ((unsigned)iw < 64u);
                int ihc = min(max(ih, 0), 47), iwc = min(max(iw, 0), 63);
                srcoff[mf] = (ihc * 64 + iwc) * 64;
            }
            const int tap = a * 2 + b2;
            #pragma unroll
            for (int cc = 0; cc < 2; ++cc) {
                const int kbase = cc * 32 + kg * 8;
                short8 av[4];
                #pragma unroll
                for (int mf = 0; mf < 4; ++mf) {
                    short8 v = *(const short8*)(ib + srcoff[mf] + kbase);
                    av[mf] = val[mf] ? v : z8;
                }
                #pragma unroll
                for (int nf = 0; nf < 2; ++nf) {
                    short8 bfr = *(const short8*)(smem
                        + (tap * 32 + nf * 16) * 128 + cc * 64 + bloff);
                    #pragma unroll
                    for (int mf = 0; mf < 4; ++mf)
                        acc[mf][nf] = __builtin_amdgcn_mfma_f32_16x16x32_bf16(
                            av[mf], bfr, acc[mf][nf], 0, 0, 0);
                }
            }
        }
    }

    const float* bs = bs0 + l * 32;
    const float* bb = bb0 + l * 32;
    const float* bm = bm0 + l * 32;
    const float* bv = bv0 + l * 32;
    ushort* ob = out + (size_t)slot * 12288 * 32;
    #pragma unroll
    for (int nf = 0; nf < 2; ++nf) {
        const int col = nf * 16 + lr;
        const float inv = bs[col] * rsqrtf(bv[col] + EPSF);
        const float beta = bb[col] - bm[col] * inv;
        #pragma unroll
        for (int mf = 0; mf < 4; ++mf) {
            #pragma unroll
            for (int j = 0; j < 4; ++j) {
                int m = m0 + mf * 16 + kg * 4 + j;
                int q = m >> 6, r = m & 63;
                int sp = (2 * q + ph) * 128 + (2 * r + pw);
                float y = fmaxf(fmaf(acc[mf][nf][j], inv, beta), 0.f);
                ob[(size_t)sp * 32 + col] = f2bf(y);
            }
        }
    }
}

// ---------------- conv6 (32->1) + bias, fp32 out ---------------------------
__global__ __launch_bounds__(256) void k_conv6(
    const ushort* __restrict__ x5,    // [slot][12288][32]
    float* __restrict__ cost,         // [98][12288]
    const float* __restrict__ w0,     // cw6 base [L][32][3][3]
    const float* __restrict__ cb6, int d0)
{
    const int sp = blockIdx.x * 256 + threadIdx.x;
    const int slot = blockIdx.z;
    const int p = d0 + slot;
    const int l = p / 49;
    const float* w = w0 + l * 288;
    const int oh = sp >> 7, ow = sp & 127;
    float acc = 0.f;
    #pragma unroll
    for (int kh = 0; kh < 3; ++kh) {
        const int ih = oh - 1 + kh;
        if (ih < 0 || ih >= 96) continue;
        #pragma unroll
        for (int kw = 0; kw < 3; ++kw) {
            const int iw = ow - 1 + kw;
            if (iw < 0 || iw >= 128) continue;
            const ushort* q = x5 + ((size_t)slot * 12288 + ih * 128 + iw) * 32;
            const int tap = kh * 3 + kw;
            #pragma unroll
            for (int g = 0; g < 4; ++g) {
                uint4 v = *(const uint4*)(q + g * 8);
                const uint* vw = (const uint*)&v;
                #pragma unroll
                for (int t = 0; t < 4; ++t) {
                    int ci = g * 8 + t * 2;
                    acc = fmaf(bf2f((ushort)(vw[t] & 0xFFFF)), w[ci * 9 + tap], acc);
                    acc = fmaf(bf2f((ushort)(vw[t] >> 16)), w[(ci + 1) * 9 + tap], acc);
                }
            }
        }
    }
    cost[(size_t)p * 12288 + sp] = acc + cb6[l];
}

// ---------------- DAP ------------------------------------------------------
__global__ __launch_bounds__(256) void k_dap(
    const float* __restrict__ cost, const float* __restrict__ dw,
    float* __restrict__ out)
{
    const int sp = blockIdx.x * 256 + threadIdx.x;
    const int p = blockIdx.y;
    const float* dr = dw + p * 49;
    float acc = 0.f;
    #pragma unroll
    for (int q = 0; q < 49; ++q)
        acc = fmaf(dr[q], cost[(size_t)q * 12288 + sp], acc);
    out[(size_t)p * 12288 + sp] = acc;
}

// ---------------------------------------------------------------------------
extern "C" void kernel_launch(void* const* d_in, const int* in_sizes, int n_in,
                              void* d_out, int out_size, void* d_ws, size_t ws_size,
                              hipStream_t stream)
{
    const float* fm1_0 = (const float*)d_in[0];
    const float* fm2_0 = (const float*)d_in[1];
    const float* fm1_1 = (const float*)d_in[2];
    const float* fm2_1 = (const float*)d_in[3];
    const float* coords = (const float*)d_in[4];
    const float* cw1  = (const float*)d_in[5];
    const float* cw2  = (const float*)d_in[6];
    const float* cw3  = (const float*)d_in[7];
    const float* cw4  = (const float*)d_in[8];
    const float* ctw5 = (const float*)d_in[9];
    const float* cw6  = (const float*)d_in[10];
    const float* cb6  = (const float*)d_in[11];
    const float* bn[5][4];
    for (int j = 0; j < 5; ++j)
        for (int k = 0; k < 4; ++k)
            bn[j][k] = (const float*)d_in[12 + j * 4 + k];
    const float* dap = (const float*)d_in[32];
    float* out = (float*)d_out;

    // ---- workspace: bufA | bufB | grouped weights | cost ----
    const size_t A_US = 786432;    // per-slot: max(x0, x2, x4)
    const size_t B_US = 1179648;   // per-slot: max(x1, x3, x5)
    const size_t W1 = 9 * 96 * 64, W2 = 9 * 128 * 96, W3 = 9 * 128 * 128;
    const size_t W4 = 9 * 64 * 128, W5 = 16 * 32 * 64;
    const size_t W_US = 2 * (W1 + W2 + W3 + W4 + W5);
    const size_t COSTF = (size_t)98 * 12288;

    int DC = 1;
    for (int cand : {98, 66, 49, 42, 33, 25, 17, 13, 9, 7, 5, 3, 2, 1}) {
        size_t need = (A_US + B_US) * (size_t)cand * 2 + W_US * 2 + COSTF * 4 + 4096;
        if (need <= ws_size) { DC = cand; break; }
    }

    ushort* bufA = (ushort*)d_ws;
    ushort* bufB = bufA + A_US * DC;
    ushort* wp = bufB + B_US * DC;
    ushort* wr1 = wp; wp += 2 * W1;
    ushort* wr2 = wp; wp += 2 * W2;
    ushort* wr3 = wp; wp += 2 * W3;
    ushort* wr4 = wp; wp += 2 * W4;
    ushort* wr5 = wp; wp += 2 * W5;
    float* cost = (float*)wp;

    // ---- weight repack (grouped: level l at +l*Wk) ----
    for (int l = 0; l < 2; ++l) {
        k_repack_conv<<<dim3(216), 256, 0, stream>>>(cw1 + (size_t)l * W1, wr1 + l * W1, 96, 64);
        k_repack_conv<<<dim3(432), 256, 0, stream>>>(cw2 + (size_t)l * W2, wr2 + l * W2, 128, 96);
        k_repack_conv<<<dim3(576), 256, 0, stream>>>(cw3 + (size_t)l * W3, wr3 + l * W3, 128, 128);
        k_repack_conv<<<dim3(288), 256, 0, stream>>>(cw4 + (size_t)l * W4, wr4 + l * W4, 64, 128);
        k_repack_ct<<<dim3(128), 256, 0, stream>>>(ctw5 + (size_t)l * W5, wr5 + l * W5);
    }

    for (int d0 = 0; d0 < 98; d0 += DC) {
        const int ndd = min(DC, 98 - d0);
        k_sample_nhwc<<<dim3(48, 1, ndd), 256, 0, stream>>>(
            fm1_0, fm1_1, fm2_0, fm2_1, coords, bufA, d0);
        k_conv_mfma<64, 96, 3, 1, 96, 128, 96, 128>
            <<<dim3(48, 2, ndd), 256, 0, stream>>>(bufA, bufB, wr1, (int)W1,
                bn[0][0], bn[0][1], bn[0][2], bn[0][3], d0);
        k_conv_mfma<96, 128, 4, 2, 96, 128, 48, 64>
            <<<dim3(12, 2, ndd), 256, 0, stream>>>(bufB, bufA, wr2, (int)W2,
                bn[1][0], bn[1][1], bn[1][2], bn[1][3], d0);
        k_conv_mfma<128, 128, 4, 1, 48, 64, 48, 64>
            <<<dim3(12, 2, ndd), 256, 0, stream>>>(bufA, bufB, wr3, (int)W3,
                bn[2][0], bn[2][1], bn[2][2], bn[2][3], d0);
        k_conv_mfma<128, 64, 4, 1, 48, 64, 48, 64>
            <<<dim3(12, 1, ndd), 256, 0, stream>>>(bufB, bufA, wr4, (int)W4,
                bn[3][0], bn[3][1], bn[3][2], bn[3][3], d0);
        k_convt_mfma<<<dim3(12, 4, ndd), 256, 0, stream>>>(bufA, bufB, wr5,
                bn[4][0], bn[4][1], bn[4][2], bn[4][3], d0);
        k_conv6<<<dim3(48, 1, ndd), 256, 0, stream>>>(
            bufB, cost, cw6, cb6, d0);
    }
    for (int l = 0; l < 2; ++l)
        k_dap<<<dim3(48, 49), 256, 0, stream>>>(
            cost + (size_t)l * 49 * 12288, dap + (size_t)l * 49 * 49,
            out + (size_t)l * 49 * 12288);
}

// Round 7
// 1004.598 us; speedup vs baseline: 2.4132x; 1.2885x over previous
//
#include <hip/hip_runtime.h>

#define EPSF 1e-5f

typedef __attribute__((ext_vector_type(8))) short short8;
typedef __attribute__((ext_vector_type(4))) float f32x4;

__device__ __forceinline__ ushort f2bf(float x) {
    union { float f; unsigned u; } c; c.f = x;
    unsigned r = c.u + 0x7FFF + ((c.u >> 16) & 1);   // RNE
    return (ushort)(r >> 16);
}
__device__ __forceinline__ float bf2f(ushort b) {
    union { unsigned u; float f; } c; c.u = ((unsigned)b) << 16;
    return c.f;
}

// ---------------------------------------------------------------------------
// Geometry: B=1, C=32, H=96, W=128, L=2, N=7 (49 displacements/level).
// blockIdx.z spans merged (level,d) pairs p = d0 + z, p in [0,98).
// Activations NHWC bf16, unpadded:
//   x0 [slot][12288][64]  x1 [slot][12288][96]  x2,x3 [slot][3072][128]
//   x4 [slot][3072][64]   x5 [slot][12288][32]
// Weights repacked [l][tap][COUT][CIN] bf16.
// ---------------------------------------------------------------------------

__global__ __launch_bounds__(256) void k_repack_conv(
    const float* __restrict__ src, ushort* __restrict__ dst, int CO, int CI)
{
    int idx = blockIdx.x * 256 + threadIdx.x;
    if (idx >= CO * CI * 9) return;
    int co = idx / (CI * 9);
    int rem = idx % (CI * 9);
    int ci = rem / 9, tap = rem % 9;
    dst[((size_t)tap * CO + co) * CI + ci] = f2bf(src[idx]);
}

// ctw5 [64][32][4][4] fp32 -> [parity(4)][tap(4)][32co][64ci] bf16
__global__ __launch_bounds__(256) void k_repack_ct(
    const float* __restrict__ src, ushort* __restrict__ dst)
{
    int idx = blockIdx.x * 256 + threadIdx.x;
    if (idx >= 4 * 4 * 32 * 64) return;
    int ci = idx & 63;
    int t = idx >> 6;
    int co = t & 31; t >>= 5;
    int tap = t & 3;
    int parity = t >> 2;
    int ph = parity >> 1, pw = parity & 1;
    int a = tap >> 1, b = tap & 1;
    int kh = ((ph + 1) & 1) + 2 * a;
    int kw = ((pw + 1) & 1) + 2 * b;
    dst[idx] = f2bf(src[((ci * 32 + co) * 4 + kh) * 4 + kw]);
}

// ---------------- sample + concat -> x0 [slot][12288][64] ------------------
__global__ __launch_bounds__(256) void k_sample_nhwc(
    const float* __restrict__ f1_0, const float* __restrict__ f1_1,
    const float* __restrict__ f2_0, const float* __restrict__ f2_1,
    const float* __restrict__ coords, ushort* __restrict__ x0, int d0)
{
    const int HW = 12288;
    const int sp = blockIdx.x * 256 + threadIdx.x;
    const int slot = blockIdx.z;
    const int p = d0 + slot;
    const int l = p / 49;
    const int d = p - l * 49;
    const int du = d / 7, dv = d % 7;
    const float inv_scale = l ? 0.5f : 1.0f;
    const float* f1 = l ? f1_1 : f1_0;
    const float* f2 = l ? f2_1 : f2_0;

    float cx = coords[sp] * inv_scale + (float)(du - 3);
    float cy = coords[HW + sp] * inv_scale + (float)(dv - 3);
    float xf = floorf(cx), yf = floorf(cy);
    float wx = cx - xf, wy = cy - yf;
    int xi = (int)xf, yi = (int)yf;
    float vx0 = (xf >= 0.f && xf <= 127.f) ? 1.f : 0.f;
    float vx1 = (xf + 1.f >= 0.f && xf + 1.f <= 127.f) ? 1.f : 0.f;
    float vy0 = (yf >= 0.f && yf <= 95.f) ? 1.f : 0.f;
    float vy1 = (yf + 1.f >= 0.f && yf + 1.f <= 95.f) ? 1.f : 0.f;
    int x0i = min(max(xi, 0), 127), x1i = min(max(xi + 1, 0), 127);
    int y0i = min(max(yi, 0), 95),  y1i = min(max(yi + 1, 0), 95);
    float w00 = (1.f - wx) * (1.f - wy) * vx0 * vy0;
    float w01 = wx * (1.f - wy) * vx1 * vy0;
    float w10 = (1.f - wx) * wy * vx0 * vy1;
    float w11 = wx * wy * vx1 * vy1;
    int o00 = y0i * 128 + x0i, o01 = y0i * 128 + x1i;
    int o10 = y1i * 128 + x0i, o11 = y1i * 128 + x1i;

    ushort* dst = x0 + ((size_t)slot * HW + sp) * 64;
    #pragma unroll
    for (int g = 0; g < 4; ++g) {               // f1 channels 0..31
        uint4 pk;
        uint* pw_ = (uint*)&pk;
        #pragma unroll
        for (int q = 0; q < 4; ++q) {
            int c = g * 8 + q * 2;
            pw_[q] = (uint)f2bf(f1[(size_t)c * HW + sp])
                   | ((uint)f2bf(f1[(size_t)(c + 1) * HW + sp]) << 16);
        }
        *(uint4*)(dst + g * 8) = pk;
    }
    #pragma unroll
    for (int g = 0; g < 4; ++g) {               // sampled f2 channels 32..63
        uint4 pk;
        uint* pw_ = (uint*)&pk;
        #pragma unroll
        for (int q = 0; q < 4; ++q) {
            uint wv = 0;
            #pragma unroll
            for (int h = 0; h < 2; ++h) {
                int c = g * 8 + q * 2 + h;
                const float* fc = f2 + (size_t)c * HW;
                float s = w00 * fc[o00] + w01 * fc[o01] + w10 * fc[o10] + w11 * fc[o11];
                wv |= ((uint)f2bf(s)) << (16 * h);
            }
            pw_[q] = wv;
        }
        *(uint4*)(dst + 32 + g * 8) = pk;
    }
}

// ---------------- LDS-fed conv3x3 stride-1 (+BN+ReLU) ----------------------
// 4 waves; out-tile 4 rows x 64 cols x ROWS co.  A-window 6x66 pos x 64ch
// (128B/pos, key (pos&7)<<4 — round-4-proven conflict-free).  B paged by
// kh-row (3 taps x ROWS x 128B), double-buffered, reg-prefetched (T14).
template <int CIN, int COUT, int ROWS, int IH, int IW>
__global__ __launch_bounds__(256) void k_conv_lds(
    const ushort* __restrict__ in, ushort* __restrict__ out,
    const ushort* __restrict__ wbase, int wlstride,
    const float* __restrict__ bs0, const float* __restrict__ bb0,
    const float* __restrict__ bm0, const float* __restrict__ bv0, int d0)
{
    constexpr int NFT = ROWS / 16;
    constexpr int CC = CIN / 64;
    constexpr int NCT = IW / 64;
    constexpr int AB = 6 * 66 * 128;             // 50688 B
    constexpr int PB = 3 * ROWS * 128;           // B page bytes
    constexpr int SA = (AB + 4095) / 4096;       // 13
    constexpr int SB = (PB + 4095) / 4096;       // 5 (ROWS=48) / 6 (ROWS=64)
    constexpr int NPH = 3 * CC;
    __shared__ __align__(16) char smem[AB + 2 * PB];
    char* As = smem;

    const int tid = threadIdx.x;
    const int lane = tid & 63, wid = tid >> 6;
    const int lr = lane & 15, kg = lane >> 4;
    const int rt = (int)blockIdx.x / NCT, ct = (int)blockIdx.x % NCT;
    const int r0 = rt * 4, c0 = ct * 64;
    const int co0 = blockIdx.y * ROWS;
    const int slot = blockIdx.z;
    const int l = (d0 + slot) / 49;

    // ---- staging tables (once) ----
    int aoff[SA]; unsigned awr = 0, avalid = 0;
    #pragma unroll
    for (int i = 0; i < SA; ++i) {
        int lin = i * 4096 + tid * 16;
        bool wr = lin < AB;
        int linc = wr ? lin : 0;
        int pos = linc >> 7;
        int prow = (pos * 994) >> 16;            // /66 for pos<396
        int pcol = pos - prow * 66;
        int grow = r0 - 1 + prow, gcol = c0 - 1 + pcol;
        bool ok = wr && ((unsigned)grow < (unsigned)IH) && ((unsigned)gcol < (unsigned)IW);
        if (wr) awr |= 1u << i;
        if (ok) avalid |= 1u << i;
        int growc = min(max(grow, 0), IH - 1), gcolc = min(max(gcol, 0), IW - 1);
        aoff[i] = (growc * IW + gcolc) * CIN + ((linc & 127) >> 1);
    }
    int boff[SB]; unsigned bmask = 0;
    #pragma unroll
    for (int i = 0; i < SB; ++i) {
        int lin = i * 4096 + tid * 16;
        if (lin < PB) bmask |= 1u << i;
        int lc = min(lin, PB - 16);
        int rowidx = lc >> 7;
        int tpg = rowidx / ROWS, r = rowidx - tpg * ROWS;
        boff[i] = (tpg * COUT + co0 + r) * CIN + ((lc & 127) >> 1);
    }

    const ushort* ib = in + (size_t)slot * IH * IW * CIN;
    const ushort* wl = wbase + (size_t)l * wlstride;
    const short8 z8 = {0, 0, 0, 0, 0, 0, 0, 0};

    short8 stgA[SA], stgB[SB];
    auto loadA = [&](int cc) {
        #pragma unroll
        for (int i = 0; i < SA; ++i) {
            if ((avalid >> i) & 1) stgA[i] = *(const short8*)(ib + aoff[i] + cc * 64);
            else stgA[i] = z8;
        }
    };
    auto writeA = [&]() {
        #pragma unroll
        for (int i = 0; i < SA; ++i) {
            int lin = i * 4096 + tid * 16;
            if ((awr >> i) & 1)
                *(short8*)(As + (lin ^ (((lin >> 7) & 7) << 4))) = stgA[i];
        }
    };
    auto loadB = [&](int ps) {
        int pg = ps % 3, cc = ps / 3;
        const ushort* src = wl + pg * (3 * COUT * CIN) + cc * 64;
        #pragma unroll
        for (int i = 0; i < SB; ++i)
            if ((bmask >> i) & 1) stgB[i] = *(const short8*)(src + boff[i]);
    };
    auto writeB = [&](int ps) {
        char* Bs = smem + AB + (ps & 1) * PB;
        #pragma unroll
        for (int i = 0; i < SB; ++i) {
            int lin = i * 4096 + tid * 16;
            if ((bmask >> i) & 1)
                *(short8*)(Bs + (lin ^ (((lin >> 7) & 7) << 4))) = stgB[i];
        }
    };

    f32x4 acc[4][NFT];
    #pragma unroll
    for (int mf = 0; mf < 4; ++mf)
        #pragma unroll
        for (int nf = 0; nf < NFT; ++nf)
            acc[mf][nf] = (f32x4){0.f, 0.f, 0.f, 0.f};

    loadA(0); loadB(0);
    writeA(); writeB(0);
    __syncthreads();

    #pragma unroll 1
    for (int ps = 0; ps < NPH; ++ps) {
        const int pg = ps % 3;                    // = kh
        const bool hasNext = (ps + 1 < NPH);
        const bool newA = (CC > 1) && (pg == 2) && hasNext;
        if (hasNext) loadB(ps + 1);               // T14: issue before compute
        if (newA) loadA(ps / 3 + 1);

        const char* Bs = smem + AB + (ps & 1) * PB;
        #pragma unroll
        for (int kw = 0; kw < 3; ++kw) {
            const int spb = (wid + pg) * 66 + lr + kw;
            #pragma unroll
            for (int ks = 0; ks < 2; ++ks) {
                short8 a[4];
                #pragma unroll
                for (int mf = 0; mf < 4; ++mf) {
                    int sp = spb + mf * 16;
                    int ad = sp * 128 + ((ks * 64 + kg * 16) ^ ((sp & 7) << 4));
                    a[mf] = *(const short8*)(As + ad);
                }
                #pragma unroll
                for (int nf = 0; nf < NFT; ++nf) {
                    int rb = kw * ROWS + nf * 16 + lr;
                    int bd = rb * 128 + ((ks * 64 + kg * 16) ^ ((rb & 7) << 4));
                    short8 b = *(const short8*)(Bs + bd);
                    #pragma unroll
                    for (int mf = 0; mf < 4; ++mf)
                        acc[mf][nf] = __builtin_amdgcn_mfma_f32_16x16x32_bf16(
                            a[mf], b, acc[mf][nf], 0, 0, 0);
                }
            }
        }

        __syncthreads();
        if (hasNext) writeB(ps + 1);
        if (newA) writeA();
        if (hasNext) __syncthreads();
    }

    // ---- epilogue: BN + ReLU, NHWC write ----
    const float* bs = bs0 + l * COUT;
    const float* bb = bb0 + l * COUT;
    const float* bm = bm0 + l * COUT;
    const float* bv = bv0 + l * COUT;
    ushort* ob = out + (size_t)slot * IH * IW * COUT;
    const int orow = r0 + wid;
    #pragma unroll
    for (int nf = 0; nf < NFT; ++nf) {
        const int col = co0 + nf * 16 + lr;
        const float inv = bs[col] * rsqrtf(bv[col] + EPSF);
        const float beta = bb[col] - bm[col] * inv;
        #pragma unroll
        for (int mf = 0; mf < 4; ++mf) {
            #pragma unroll
            for (int j = 0; j < 4; ++j) {
                int ocol = c0 + mf * 16 + kg * 4 + j;
                float y = fmaxf(fmaf(acc[mf][nf][j], inv, beta), 0.f);
                ob[((size_t)orow * IW + ocol) * COUT + col] = f2bf(y);
            }
        }
    }
}

// ---------------- conv2 (stride-2): round-6 version ------------------------
template <int CIN, int COUT, int NFT, int STRIDE, int IH, int IW, int OH, int OW>
__global__ __launch_bounds__(256) void k_conv_mfma(
    const ushort* __restrict__ in, ushort* __restrict__ out,
    const ushort* __restrict__ wbase, int wlstride,
    const float* __restrict__ bs0, const float* __restrict__ bb0,
    const float* __restrict__ bm0, const float* __restrict__ bv0, int d0)
{
    constexpr int CC = CIN / 32;
    constexpr int ROWS = NFT * 16;
    constexpr int SLICE = 9 * ROWS * 64;
    constexpr int S = (SLICE + 4095) / 4096;
    constexpr int OWS = (OW == 128) ? 7 : 6;
    __shared__ __align__(16) char smem[SLICE];

    const int tid = threadIdx.x;
    const int lane = tid & 63, wid = tid >> 6;
    const int lr = lane & 15, kg = lane >> 4;
    const int m0 = blockIdx.x * 256 + wid * 64;
    const int co0 = blockIdx.y * ROWS;
    const int slot = blockIdx.z;
    const int l = (d0 + slot) / 49;

    int soff[S], sdst[S];
    bool smask[S];
    #pragma unroll
    for (int i = 0; i < S; ++i) {
        int lin = i * 4096 + tid * 16;
        smask[i] = lin < SLICE;
        int rowidx = lin >> 6;
        int tap = rowidx / ROWS;
        int r = rowidx - tap * ROWS;
        soff[i] = (tap * COUT + r) * (CIN * 2) + (lin & 63);
        sdst[i] = lin ^ ((rowidx & 3) << 4);
    }
    const char* wsrc = (const char*)(wbase + (size_t)l * wlstride)
                     + (size_t)co0 * (CIN * 2);

    int bh[4], bw[4];
    #pragma unroll
    for (int mf = 0; mf < 4; ++mf) {
        int m = m0 + mf * 16 + lr;
        bh[mf] = (m >> OWS) * STRIDE - 1;
        bw[mf] = (m & (OW - 1)) * STRIDE - 1;
    }
    const ushort* ib = in + (size_t)slot * IH * IW * CIN;
    const int bloff = lr * 64 + ((kg * 16) ^ ((lr & 3) << 4));

    const short8 z8 = {0, 0, 0, 0, 0, 0, 0, 0};
    f32x4 acc[4][NFT];
    #pragma unroll
    for (int mf = 0; mf < 4; ++mf)
        #pragma unroll
        for (int nf = 0; nf < NFT; ++nf)
            acc[mf][nf] = (f32x4){0.f, 0.f, 0.f, 0.f};

    short8 stg[S];
    #pragma unroll
    for (int i = 0; i < S; ++i)
        if (smask[i]) stg[i] = *(const short8*)(wsrc + soff[i]);

    #pragma unroll
    for (int cc = 0; cc < CC; ++cc) {
        if (cc) __syncthreads();
        #pragma unroll
        for (int i = 0; i < S; ++i)
            if (smask[i]) *(short8*)(smem + sdst[i]) = stg[i];
        __syncthreads();
        if (cc + 1 < CC) {
            #pragma unroll
            for (int i = 0; i < S; ++i)
                if (smask[i]) stg[i] = *(const short8*)(wsrc + (cc + 1) * 64 + soff[i]);
        }
        const int kbase = cc * 32 + kg * 8;
        #pragma unroll
        for (int kh = 0; kh < 3; ++kh) {
            #pragma unroll
            for (int kw = 0; kw < 3; ++kw) {
                short8 a[4];
                #pragma unroll
                for (int mf = 0; mf < 4; ++mf) {
                    int ih = bh[mf] + kh, iw = bw[mf] + kw;
                    bool v = ((unsigned)ih < (unsigned)IH) && ((unsigned)iw < (unsigned)IW);
                    int ihc = min(max(ih, 0), IH - 1);
                    int iwc = min(max(iw, 0), IW - 1);
                    short8 t = *(const short8*)(ib + (ihc * IW + iwc) * CIN + kbase);
                    a[mf] = v ? t : z8;
                }
                const int tb = (kh * 3 + kw) * (ROWS * 64);
                #pragma unroll
                for (int nf = 0; nf < NFT; ++nf) {
                    short8 b = *(const short8*)(smem + tb + nf * 1024 + bloff);
                    #pragma unroll
                    for (int mf = 0; mf < 4; ++mf)
                        acc[mf][nf] = __builtin_amdgcn_mfma_f32_16x16x32_bf16(
                            a[mf], b, acc[mf][nf], 0, 0, 0);
                }
            }
        }
    }

    const float* bs = bs0 + l * COUT;
    const float* bb = bb0 + l * COUT;
    const float* bm = bm0 + l * COUT;
    const float* bv = bv0 + l * COUT;
    ushort* ob = out + (size_t)slot * OH * OW * COUT;
    #pragma unroll
    for (int nf = 0; nf < NFT; ++nf) {
        const int col = co0 + nf * 16 + lr;
        const float inv = bs[col] * rsqrtf(bv[col] + EPSF);
        const float beta = bb[col] - bm[col] * inv;
        #pragma unroll
        for (int mf = 0; mf < 4; ++mf) {
            #pragma unroll
            for (int j = 0; j < 4; ++j) {
                int row = m0 + mf * 16 + kg * 4 + j;
                float y = fmaxf(fmaf(acc[mf][nf][j], inv, beta), 0.f);
                ob[(size_t)row * COUT + col] = f2bf(y);
            }
        }
    }
}

// ---------------- MFMA convT4x4 s2 (+BN+ReLU), weights via LDS -------------
// in [slot][3072][64] -> out [slot][12288][32]; w [l][parity][tap][32][64]
__global__ __launch_bounds__(256) void k_convt_mfma(
    const ushort* __restrict__ in, ushort* __restrict__ out,
    const ushort* __restrict__ wbase,
    const float* __restrict__ bs0, const float* __restrict__ bb0,
    const float* __restrict__ bm0, const float* __restrict__ bv0, int d0)
{
    constexpr int SLICE = 4 * 32 * 128;
    constexpr int S = 4;
    __shared__ __align__(16) char smem[SLICE];

    const int tid = threadIdx.x;
    const int lane = tid & 63, wid = tid >> 6;
    const int lr = lane & 15, kg = lane >> 4;
    const int m0 = blockIdx.x * 256 + wid * 64;
    const int parity = blockIdx.y;
    const int slot = blockIdx.z;
    const int l = (d0 + slot) / 49;
    const int ph = parity >> 1, pw = parity & 1;
    const int kh0 = (ph + 1) & 1, kw0 = (pw + 1) & 1;

    {
        const char* wsrc = (const char*)(wbase + (size_t)l * (16 * 32 * 64));
        #pragma unroll
        for (int i = 0; i < S; ++i) {
            int lin = i * 4096 + tid * 16;
            int rowidx = lin >> 7;
            int tap = rowidx >> 5, r = rowidx & 31;
            short8 v = *(const short8*)(wsrc
                + (((size_t)(parity * 4 + tap) * 32 + r) * 64) * 2 + (lin & 127));
            *(short8*)(smem + (lin ^ ((rowidx & 7) << 4))) = v;
        }
    }
    __syncthreads();

    int ihA[4], iwA[4];
    #pragma unroll
    for (int mf = 0; mf < 4; ++mf) {
        int m = m0 + mf * 16 + lr;
        int q = m >> 6, r = m & 63;
        ihA[mf] = (2 * q + ph + 1 - kh0) >> 1;
        iwA[mf] = (2 * r + pw + 1 - kw0) >> 1;
    }
    const ushort* ib = in + (size_t)slot * 3072 * 64;

    const short8 z8 = {0, 0, 0, 0, 0, 0, 0, 0};
    f32x4 acc[4][2];
    #pragma unroll
    for (int mf = 0; mf < 4; ++mf)
        #pragma unroll
        for (int nf = 0; nf < 2; ++nf)
            acc[mf][nf] = (f32x4){0.f, 0.f, 0.f, 0.f};

    #pragma unroll
    for (int a = 0; a < 2; ++a) {
        #pragma unroll
        for (int b2 = 0; b2 < 2; ++b2) {
            int srcoff[4]; bool val[4];
            #pragma unroll
            for (int mf = 0; mf < 4; ++mf) {
                int ih = ihA[mf] - a;
                int iw = iwA[mf] - b2;
                val[mf] = ((unsigned)ih < 48u) && ((unsigned)iw < 64u);
                int ihc = min(max(ih, 0), 47), iwc = min(max(iw, 0), 63);
                srcoff[mf] = (ihc * 64 + iwc) * 64;
            }
            const int tap = a * 2 + b2;
            #pragma unroll
            for (int cc = 0; cc < 2; ++cc) {
                const int kbase = cc * 32 + kg * 8;
                short8 av[4];
                #pragma unroll
                for (int mf = 0; mf < 4; ++mf) {
                    short8 v = *(const short8*)(ib + srcoff[mf] + kbase);
                    av[mf] = val[mf] ? v : z8;
                }
                #pragma unroll
                for (int nf = 0; nf < 2; ++nf) {
                    short8 bfr = *(const short8*)(smem
                        + (tap * 32 + nf * 16 + lr) * 128
                        + ((cc * 64 + kg * 16) ^ ((lr & 7) << 4)));
                    #pragma unroll
                    for (int mf = 0; mf < 4; ++mf)
                        acc[mf][nf] = __builtin_amdgcn_mfma_f32_16x16x32_bf16(
                            av[mf], bfr, acc[mf][nf], 0, 0, 0);
                }
            }
        }
    }

    const float* bs = bs0 + l * 32;
    const float* bb = bb0 + l * 32;
    const float* bm = bm0 + l * 32;
    const float* bv = bv0 + l * 32;
    ushort* ob = out + (size_t)slot * 12288 * 32;
    #pragma unroll
    for (int nf = 0; nf < 2; ++nf) {
        const int col = nf * 16 + lr;
        const float inv = bs[col] * rsqrtf(bv[col] + EPSF);
        const float beta = bb[col] - bm[col] * inv;
        #pragma unroll
        for (int mf = 0; mf < 4; ++mf) {
            #pragma unroll
            for (int j = 0; j < 4; ++j) {
                int m = m0 + mf * 16 + kg * 4 + j;
                int q = m >> 6, r = m & 63;
                int sp = (2 * q + ph) * 128 + (2 * r + pw);
                float y = fmaxf(fmaf(acc[mf][nf][j], inv, beta), 0.f);
                ob[(size_t)sp * 32 + col] = f2bf(y);
            }
        }
    }
}

// ---------------- conv6 (32->1) + bias, fp32 out ---------------------------
__global__ __launch_bounds__(256) void k_conv6(
    const ushort* __restrict__ x5, float* __restrict__ cost,
    const float* __restrict__ w0, const float* __restrict__ cb6, int d0)
{
    const int sp = blockIdx.x * 256 + threadIdx.x;
    const int slot = blockIdx.z;
    const int p = d0 + slot;
    const int l = p / 49;
    const float* w = w0 + l * 288;
    const int oh = sp >> 7, ow = sp & 127;
    float acc = 0.f;
    #pragma unroll
    for (int kh = 0; kh < 3; ++kh) {
        const int ih = oh - 1 + kh;
        if (ih < 0 || ih >= 96) continue;
        #pragma unroll
        for (int kw = 0; kw < 3; ++kw) {
            const int iw = ow - 1 + kw;
            if (iw < 0 || iw >= 128) continue;
            const ushort* q = x5 + ((size_t)slot * 12288 + ih * 128 + iw) * 32;
            const int tap = kh * 3 + kw;
            #pragma unroll
            for (int g = 0; g < 4; ++g) {
                uint4 v = *(const uint4*)(q + g * 8);
                const uint* vw = (const uint*)&v;
                #pragma unroll
                for (int t = 0; t < 4; ++t) {
                    int ci = g * 8 + t * 2;
                    acc = fmaf(bf2f((ushort)(vw[t] & 0xFFFF)), w[ci * 9 + tap], acc);
                    acc = fmaf(bf2f((ushort)(vw[t] >> 16)), w[(ci + 1) * 9 + tap], acc);
                }
            }
        }
    }
    cost[(size_t)p * 12288 + sp] = acc + cb6[l];
}

// ---------------- DAP ------------------------------------------------------
__global__ __launch_bounds__(256) void k_dap(
    const float* __restrict__ cost, const float* __restrict__ dw,
    float* __restrict__ out)
{
    const int sp = blockIdx.x * 256 + threadIdx.x;
    const int p = blockIdx.y;
    const float* dr = dw + p * 49;
    float acc = 0.f;
    #pragma unroll
    for (int q = 0; q < 49; ++q)
        acc = fmaf(dr[q], cost[(size_t)q * 12288 + sp], acc);
    out[(size_t)p * 12288 + sp] = acc;
}

// ---------------------------------------------------------------------------
extern "C" void kernel_launch(void* const* d_in, const int* in_sizes, int n_in,
                              void* d_out, int out_size, void* d_ws, size_t ws_size,
                              hipStream_t stream)
{
    const float* fm1_0 = (const float*)d_in[0];
    const float* fm2_0 = (const float*)d_in[1];
    const float* fm1_1 = (const float*)d_in[2];
    const float* fm2_1 = (const float*)d_in[3];
    const float* coords = (const float*)d_in[4];
    const float* cw1  = (const float*)d_in[5];
    const float* cw2  = (const float*)d_in[6];
    const float* cw3  = (const float*)d_in[7];
    const float* cw4  = (const float*)d_in[8];
    const float* ctw5 = (const float*)d_in[9];
    const float* cw6  = (const float*)d_in[10];
    const float* cb6  = (const float*)d_in[11];
    const float* bn[5][4];
    for (int j = 0; j < 5; ++j)
        for (int k = 0; k < 4; ++k)
            bn[j][k] = (const float*)d_in[12 + j * 4 + k];
    const float* dap = (const float*)d_in[32];
    float* out = (float*)d_out;

    // ---- workspace: bufA | bufB | grouped weights | cost ----
    const size_t A_US = 786432;    // per-slot: max(x0, x2, x4)
    const size_t B_US = 1179648;   // per-slot: max(x1, x3, x5)
    const size_t W1 = 9 * 96 * 64, W2 = 9 * 128 * 96, W3 = 9 * 128 * 128;
    const size_t W4 = 9 * 64 * 128, W5 = 16 * 32 * 64;
    const size_t W_US = 2 * (W1 + W2 + W3 + W4 + W5);
    const size_t COSTF = (size_t)98 * 12288;

    int DC = 1;
    for (int cand : {98, 66, 49, 42, 33, 25, 17, 13, 9, 7, 5, 3, 2, 1}) {
        size_t need = (A_US + B_US) * (size_t)cand * 2 + W_US * 2 + COSTF * 4 + 4096;
        if (need <= ws_size) { DC = cand; break; }
    }

    ushort* bufA = (ushort*)d_ws;
    ushort* bufB = bufA + A_US * DC;
    ushort* wp = bufB + B_US * DC;
    ushort* wr1 = wp; wp += 2 * W1;
    ushort* wr2 = wp; wp += 2 * W2;
    ushort* wr3 = wp; wp += 2 * W3;
    ushort* wr4 = wp; wp += 2 * W4;
    ushort* wr5 = wp; wp += 2 * W5;
    float* cost = (float*)wp;

    for (int l = 0; l < 2; ++l) {
        k_repack_conv<<<dim3(216), 256, 0, stream>>>(cw1 + (size_t)l * W1, wr1 + l * W1, 96, 64);
        k_repack_conv<<<dim3(432), 256, 0, stream>>>(cw2 + (size_t)l * W2, wr2 + l * W2, 128, 96);
        k_repack_conv<<<dim3(576), 256, 0, stream>>>(cw3 + (size_t)l * W3, wr3 + l * W3, 128, 128);
        k_repack_conv<<<dim3(288), 256, 0, stream>>>(cw4 + (size_t)l * W4, wr4 + l * W4, 64, 128);
        k_repack_ct<<<dim3(128), 256, 0, stream>>>(ctw5 + (size_t)l * W5, wr5 + l * W5);
    }

    for (int d0 = 0; d0 < 98; d0 += DC) {
        const int ndd = min(DC, 98 - d0);
        k_sample_nhwc<<<dim3(48, 1, ndd), 256, 0, stream>>>(
            fm1_0, fm1_1, fm2_0, fm2_1, coords, bufA, d0);
        k_conv_lds<64, 96, 48, 96, 128>
            <<<dim3(48, 2, ndd), 256, 0, stream>>>(bufA, bufB, wr1, (int)W1,
                bn[0][0], bn[0][1], bn[0][2], bn[0][3], d0);
        k_conv_mfma<96, 128, 4, 2, 96, 128, 48, 64>
            <<<dim3(12, 2, ndd), 256, 0, stream>>>(bufB, bufA, wr2, (int)W2,
                bn[1][0], bn[1][1], bn[1][2], bn[1][3], d0);
        k_conv_lds<128, 128, 64, 48, 64>
            <<<dim3(12, 2, ndd), 256, 0, stream>>>(bufA, bufB, wr3, (int)W3,
                bn[2][0], bn[2][1], bn[2][2], bn[2][3], d0);
        k_conv_lds<128, 64, 64, 48, 64>
            <<<dim3(12, 1, ndd), 256, 0, stream>>>(bufB, bufA, wr4, (int)W4,
                bn[3][0], bn[3][1], bn[3][2], bn[3][3], d0);
        k_convt_mfma<<<dim3(12, 4, ndd), 256, 0, stream>>>(bufA, bufB, wr5,
                bn[4][0], bn[4][1], bn[4][2], bn[4][3], d0);
        k_conv6<<<dim3(48, 1, ndd), 256, 0, stream>>>(
            bufB, cost, cw6, cb6, d0);
    }
    for (int l = 0; l < 2; ++l)
        k_dap<<<dim3(48, 49), 256, 0, stream>>>(
            cost + (size_t)l * 49 * 12288, dap + (size_t)l * 49 * 49,
            out + (size_t)l * 49 * 12288);
}

// Round 9
// 826.807 us; speedup vs baseline: 2.9321x; 1.2150x over previous
//
#include <hip/hip_runtime.h>

#define EPSF 1e-5f

typedef __attribute__((ext_vector_type(8))) short short8;
typedef __attribute__((ext_vector_type(4))) float f32x4;

__device__ __forceinline__ ushort f2bf(float x) {
    union { float f; unsigned u; } c; c.f = x;
    unsigned r = c.u + 0x7FFF + ((c.u >> 16) & 1);   // RNE
    return (ushort)(r >> 16);
}
__device__ __forceinline__ float bf2f(ushort b) {
    union { unsigned u; float f; } c; c.u = ((unsigned)b) << 16;
    return c.f;
}
// Uniform LDS swizzle: involution on the FULL linear byte address (rule #21:
// both-sides-or-neither).  For 128B-row layouts identical to the round-7
// proven-zero-conflict form; for 64B rows consistent by construction.
__device__ __forceinline__ int swz(int a) {
    return a ^ (((a >> 7) & 7) << 4);
}

// ---------------------------------------------------------------------------
// Geometry: B=1, C=32, H=96, W=128, L=2, N=7 (49 displacements/level).
// blockIdx.z spans merged (level,d) pairs p = d0 + z, p in [0,98).
// Activations NHWC bf16, unpadded:
//   x0 [slot][12288][64]  x1 [slot][12288][96]  x2,x3 [slot][3072][128]
//   x4 [slot][3072][64]   x5 [slot][12288][32]
// Weights repacked [l][tap][COUT][CIN] bf16.
// ---------------------------------------------------------------------------

__global__ __launch_bounds__(256) void k_repack_conv(
    const float* __restrict__ src, ushort* __restrict__ dst, int CO, int CI)
{
    int idx = blockIdx.x * 256 + threadIdx.x;
    if (idx >= CO * CI * 9) return;
    int co = idx / (CI * 9);
    int rem = idx % (CI * 9);
    int ci = rem / 9, tap = rem % 9;
    dst[((size_t)tap * CO + co) * CI + ci] = f2bf(src[idx]);
}

// ctw5 [64][32][4][4] fp32 -> [parity(4)][tap(4)][32co][64ci] bf16
__global__ __launch_bounds__(256) void k_repack_ct(
    const float* __restrict__ src, ushort* __restrict__ dst)
{
    int idx = blockIdx.x * 256 + threadIdx.x;
    if (idx >= 4 * 4 * 32 * 64) return;
    int ci = idx & 63;
    int t = idx >> 6;
    int co = t & 31; t >>= 5;
    int tap = t & 3;
    int parity = t >> 2;
    int ph = parity >> 1, pw = parity & 1;
    int a = tap >> 1, b = tap & 1;
    int kh = ((ph + 1) & 1) + 2 * a;
    int kw = ((pw + 1) & 1) + 2 * b;
    dst[idx] = f2bf(src[((ci * 32 + co) * 4 + kh) * 4 + kw]);
}

// ---------------- sample + concat -> x0 [slot][12288][64] ------------------
__global__ __launch_bounds__(256) void k_sample_nhwc(
    const float* __restrict__ f1_0, const float* __restrict__ f1_1,
    const float* __restrict__ f2_0, const float* __restrict__ f2_1,
    const float* __restrict__ coords, ushort* __restrict__ x0, int d0)
{
    const int HW = 12288;
    const int sp = blockIdx.x * 256 + threadIdx.x;
    const int slot = blockIdx.z;
    const int p = d0 + slot;
    const int l = p / 49;
    const int d = p - l * 49;
    const int du = d / 7, dv = d % 7;
    const float inv_scale = l ? 0.5f : 1.0f;
    const float* f1 = l ? f1_1 : f1_0;
    const float* f2 = l ? f2_1 : f2_0;

    float cx = coords[sp] * inv_scale + (float)(du - 3);
    float cy = coords[HW + sp] * inv_scale + (float)(dv - 3);
    float xf = floorf(cx), yf = floorf(cy);
    float wx = cx - xf, wy = cy - yf;
    int xi = (int)xf, yi = (int)yf;
    float vx0 = (xf >= 0.f && xf <= 127.f) ? 1.f : 0.f;
    float vx1 = (xf + 1.f >= 0.f && xf + 1.f <= 127.f) ? 1.f : 0.f;
    float vy0 = (yf >= 0.f && yf <= 95.f) ? 1.f : 0.f;
    float vy1 = (yf + 1.f >= 0.f && yf + 1.f <= 95.f) ? 1.f : 0.f;
    int x0i = min(max(xi, 0), 127), x1i = min(max(xi + 1, 0), 127);
    int y0i = min(max(yi, 0), 95),  y1i = min(max(yi + 1, 0), 95);
    float w00 = (1.f - wx) * (1.f - wy) * vx0 * vy0;
    float w01 = wx * (1.f - wy) * vx1 * vy0;
    float w10 = (1.f - wx) * wy * vx0 * vy1;
    float w11 = wx * wy * vx1 * vy1;
    int o00 = y0i * 128 + x0i, o01 = y0i * 128 + x1i;
    int o10 = y1i * 128 + x0i, o11 = y1i * 128 + x1i;

    ushort* dst = x0 + ((size_t)slot * HW + sp) * 64;
    #pragma unroll
    for (int g = 0; g < 4; ++g) {               // f1 channels 0..31
        uint4 pk;
        uint* pw_ = (uint*)&pk;
        #pragma unroll
        for (int q = 0; q < 4; ++q) {
            int c = g * 8 + q * 2;
            pw_[q] = (uint)f2bf(f1[(size_t)c * HW + sp])
                   | ((uint)f2bf(f1[(size_t)(c + 1) * HW + sp]) << 16);
        }
        *(uint4*)(dst + g * 8) = pk;
    }
    #pragma unroll
    for (int g = 0; g < 4; ++g) {               // sampled f2 channels 32..63
        uint4 pk;
        uint* pw_ = (uint*)&pk;
        #pragma unroll
        for (int q = 0; q < 4; ++q) {
            uint wv = 0;
            #pragma unroll
            for (int h = 0; h < 2; ++h) {
                int c = g * 8 + q * 2 + h;
                const float* fc = f2 + (size_t)c * HW;
                float s = w00 * fc[o00] + w01 * fc[o01] + w10 * fc[o10] + w11 * fc[o11];
                wv |= ((uint)f2bf(s)) << (16 * h);
            }
            pw_[q] = wv;
        }
        *(uint4*)(dst + 32 + g * 8) = pk;
    }
}

// ---------------- 8-wave LDS-fed conv3x3 stride-1 (+BN+ReLU) ---------------
// 512 thr = 8 waves; out-tile 8 rows x 64 cols x ROWS co (wave = 1 row).
// A-window 10x66 pos x 64ch (128B/pos).  B paged by kh (3 kw x ROWS x 128B),
// double-buffered, reg-prefetched (T14).
template <int CIN, int COUT, int ROWS, int IH, int IW>
__global__ __launch_bounds__(512) void k_conv_lds8(
    const ushort* __restrict__ in, ushort* __restrict__ out,
    const ushort* __restrict__ wbase, int wlstride,
    const float* __restrict__ bs0, const float* __restrict__ bb0,
    const float* __restrict__ bm0, const float* __restrict__ bv0, int d0)
{
    constexpr int NFT = ROWS / 16;
    constexpr int CC = CIN / 64;
    constexpr int NCT = IW / 64;
    constexpr int AB = 10 * 66 * 128;            // 84480 B
    constexpr int PB = 3 * ROWS * 128;           // B page bytes
    constexpr int SA = (AB + 8191) / 8192;       // 11
    constexpr int SB = (PB + 8191) / 8192;
    constexpr int NPH = 3 * CC;
    __shared__ __align__(16) char smem[AB + 2 * PB];
    char* As = smem;

    const int tid = threadIdx.x;
    const int lane = tid & 63, wid = tid >> 6;
    const int lr = lane & 15, kg = lane >> 4;
    const int rt = (int)blockIdx.x / NCT, ct = (int)blockIdx.x % NCT;
    const int r0 = rt * 8, c0 = ct * 64;
    const int co0 = blockIdx.y * ROWS;
    const int slot = blockIdx.z;
    const int l = (d0 + slot) / 49;

    // ---- staging tables (once) ----
    int aoff[SA]; unsigned awr = 0, avalid = 0;
    #pragma unroll
    for (int i = 0; i < SA; ++i) {
        int lin = i * 8192 + tid * 16;
        bool wr = lin < AB;
        int linc = wr ? lin : 0;
        int pos = linc >> 7;
        int prow = (pos * 994) >> 16;            // /66 for pos<660
        int pcol = pos - prow * 66;
        int grow = r0 - 1 + prow, gcol = c0 - 1 + pcol;
        bool ok = wr && ((unsigned)grow < (unsigned)IH) && ((unsigned)gcol < (unsigned)IW);
        if (wr) awr |= 1u << i;
        if (ok) avalid |= 1u << i;
        int growc = min(max(grow, 0), IH - 1), gcolc = min(max(gcol, 0), IW - 1);
        aoff[i] = (growc * IW + gcolc) * CIN + ((linc & 127) >> 1);
    }
    int boff[SB]; unsigned bmask = 0;
    #pragma unroll
    for (int i = 0; i < SB; ++i) {
        int lin = i * 8192 + tid * 16;
        if (lin < PB) bmask |= 1u << i;
        int lc = min(lin, PB - 16);
        int rowidx = lc >> 7;
        int tpg = rowidx / ROWS, r = rowidx - tpg * ROWS;
        boff[i] = (tpg * COUT + co0 + r) * CIN + ((lc & 127) >> 1);
    }

    const ushort* ib = in + (size_t)slot * IH * IW * CIN;
    const ushort* wl = wbase + (size_t)l * wlstride;
    const short8 z8 = {0, 0, 0, 0, 0, 0, 0, 0};

    short8 stgA[SA], stgB[SB];
    auto loadA = [&](int cc) {
        #pragma unroll
        for (int i = 0; i < SA; ++i) {
            if ((avalid >> i) & 1) stgA[i] = *(const short8*)(ib + aoff[i] + cc * 64);
            else stgA[i] = z8;
        }
    };
    auto writeA = [&]() {
        #pragma unroll
        for (int i = 0; i < SA; ++i) {
            int lin = i * 8192 + tid * 16;
            if ((awr >> i) & 1)
                *(short8*)(As + swz(lin)) = stgA[i];
        }
    };
    auto loadB = [&](int ps) {
        int pg = ps % 3, cc = ps / 3;
        const ushort* src = wl + pg * (3 * COUT * CIN) + cc * 64;
        #pragma unroll
        for (int i = 0; i < SB; ++i)
            if ((bmask >> i) & 1) stgB[i] = *(const short8*)(src + boff[i]);
    };
    auto writeB = [&](int ps) {
        char* Bs = smem + AB + (ps & 1) * PB;
        #pragma unroll
        for (int i = 0; i < SB; ++i) {
            int lin = i * 8192 + tid * 16;
            if ((bmask >> i) & 1)
                *(short8*)(Bs + swz(lin)) = stgB[i];
        }
    };

    f32x4 acc[4][NFT];
    #pragma unroll
    for (int mf = 0; mf < 4; ++mf)
        #pragma unroll
        for (int nf = 0; nf < NFT; ++nf)
            acc[mf][nf] = (f32x4){0.f, 0.f, 0.f, 0.f};

    loadA(0); loadB(0);
    writeA(); writeB(0);
    __syncthreads();

    #pragma unroll 1
    for (int ps = 0; ps < NPH; ++ps) {
        const int pg = ps % 3;                    // = kh
        const bool hasNext = (ps + 1 < NPH);
        const bool newA = (CC > 1) && (pg == 2) && hasNext;
        if (hasNext) loadB(ps + 1);               // T14: issue before compute
        if (newA) loadA(ps / 3 + 1);

        const char* Bs = smem + AB + (ps & 1) * PB;
        #pragma unroll
        for (int kw = 0; kw < 3; ++kw) {
            const int spb = (wid + pg) * 66 + lr + kw;
            #pragma unroll
            for (int ks = 0; ks < 2; ++ks) {
                short8 a[4];
                #pragma unroll
                for (int mf = 0; mf < 4; ++mf) {
                    int sp = spb + mf * 16;
                    a[mf] = *(const short8*)(As + swz(sp * 128 + ks * 64 + kg * 16));
                }
                #pragma unroll
                for (int nf = 0; nf < NFT; ++nf) {
                    int rb = kw * ROWS + nf * 16 + lr;
                    short8 b = *(const short8*)(Bs + swz(rb * 128 + ks * 64 + kg * 16));
                    #pragma unroll
                    for (int mf = 0; mf < 4; ++mf)
                        acc[mf][nf] = __builtin_amdgcn_mfma_f32_16x16x32_bf16(
                            a[mf], b, acc[mf][nf], 0, 0, 0);
                }
            }
        }

        __syncthreads();
        if (hasNext) writeB(ps + 1);
        if (newA) writeA();
        if (hasNext) __syncthreads();
    }

    // ---- epilogue: BN + ReLU, NHWC write ----
    const float* bs = bs0 + l * COUT;
    const float* bb = bb0 + l * COUT;
    const float* bm = bm0 + l * COUT;
    const float* bv = bv0 + l * COUT;
    ushort* ob = out + (size_t)slot * IH * IW * COUT;
    const int orow = r0 + wid;
    #pragma unroll
    for (int nf = 0; nf < NFT; ++nf) {
        const int col = co0 + nf * 16 + lr;
        const float inv = bs[col] * rsqrtf(bv[col] + EPSF);
        const float beta = bb[col] - bm[col] * inv;
        #pragma unroll
        for (int mf = 0; mf < 4; ++mf) {
            #pragma unroll
            for (int j = 0; j < 4; ++j) {
                int ocol = c0 + mf * 16 + kg * 4 + j;
                float y = fmaxf(fmaf(acc[mf][nf][j], inv, beta), 0.f);
                ob[((size_t)orow * IW + ocol) * COUT + col] = f2bf(y);
            }
        }
    }
}

// ---------------- 8-wave LDS-fed conv2: 3x3 stride-2 (+BN+ReLU) ------------
// x1 [96][128][96] -> x2 [48][64][128].  512 thr = 4 row-waves x 2 co-halves.
// A-window 9x130 pos x 32ch (64B/pos), CC=3 slices; B page 3kw x 128co x 64B.
__global__ __launch_bounds__(512) void k_conv_s2_8(
    const ushort* __restrict__ in, ushort* __restrict__ out,
    const ushort* __restrict__ wbase, int wlstride,
    const float* __restrict__ bs0, const float* __restrict__ bb0,
    const float* __restrict__ bm0, const float* __restrict__ bv0, int d0)
{
    constexpr int AB = 9 * 130 * 64;             // 74880 B
    constexpr int PB = 3 * 128 * 64;             // 24576 B
    constexpr int SA = (AB + 8191) / 8192;       // 10
    constexpr int SB = PB / 8192;                // 3
    constexpr int NPH = 9;                       // 3 cc x 3 kh
    __shared__ __align__(16) char smem[AB + 2 * PB];
    char* As = smem;

    const int tid = threadIdx.x;
    const int lane = tid & 63, wid = tid >> 6;
    const int lr = lane & 15, kg = lane >> 4;
    const int mw = wid >> 1, ch = wid & 1;
    const int r0 = (int)blockIdx.x * 4;
    const int slot = blockIdx.z;
    const int l = (d0 + slot) / 49;

    int aoff[SA]; unsigned awr = 0, avalid = 0;
    #pragma unroll
    for (int i = 0; i < SA; ++i) {
        int lin = i * 8192 + tid * 16;
        bool wr = lin < AB;
        int linc = wr ? lin : 0;
        int pos = linc >> 6;
        int prow = (pos * 2017) >> 18;           // /130 for pos<1170
        int pcol = pos - prow * 130;
        int grow = 2 * r0 - 1 + prow, gcol = pcol - 1;
        bool ok = wr && ((unsigned)grow < 96u) && ((unsigned)gcol < 128u);
        if (wr) awr |= 1u << i;
        if (ok) avalid |= 1u << i;
        int growc = min(max(grow, 0), 95), gcolc = min(max(gcol, 0), 127);
        aoff[i] = (growc * 128 + gcolc) * 96 + ((linc & 63) >> 1);
    }
    int boff[SB];
    #pragma unroll
    for (int i = 0; i < SB; ++i) {
        int lin = i * 8192 + tid * 16;
        int rowidx = lin >> 6;
        int tpg = rowidx >> 7, r = rowidx & 127;
        boff[i] = ((tpg * 128 + r) * 96) + ((lin & 63) >> 1);
    }

    const ushort* ib = in + (size_t)slot * 12288 * 96;
    const ushort* wl = wbase + (size_t)l * wlstride;
    const short8 z8 = {0, 0, 0, 0, 0, 0, 0, 0};

    short8 stgA[SA], stgB[SB];
    auto loadA = [&](int cc) {
        #pragma unroll
        for (int i = 0; i < SA; ++i) {
            if ((avalid >> i) & 1) stgA[i] = *(const short8*)(ib + aoff[i] + cc * 32);
            else stgA[i] = z8;
        }
    };
    auto writeA = [&]() {
        #pragma unroll
        for (int i = 0; i < SA; ++i) {
            int lin = i * 8192 + tid * 16;
            if ((awr >> i) & 1)
                *(short8*)(As + swz(lin)) = stgA[i];
        }
    };
    auto loadB = [&](int ps) {
        int pg = ps % 3, cc = ps / 3;
        const ushort* src = wl + pg * (3 * 128 * 96) + cc * 32;
        #pragma unroll
        for (int i = 0; i < SB; ++i)
            stgB[i] = *(const short8*)(src + boff[i]);
    };
    auto writeB = [&](int ps) {
        char* Bs = smem + AB + (ps & 1) * PB;
        #pragma unroll
        for (int i = 0; i < SB; ++i) {
            int lin = i * 8192 + tid * 16;
            *(short8*)(Bs + swz(lin)) = stgB[i];
        }
    };

    f32x4 acc[4][4];
    #pragma unroll
    for (int mf = 0; mf < 4; ++mf)
        #pragma unroll
        for (int nf = 0; nf < 4; ++nf)
            acc[mf][nf] = (f32x4){0.f, 0.f, 0.f, 0.f};

    loadA(0); loadB(0);
    writeA(); writeB(0);
    __syncthreads();

    #pragma unroll 1
    for (int ps = 0; ps < NPH; ++ps) {
        const int pg = ps % 3;                    // = kh
        const bool hasNext = (ps + 1 < NPH);
        const bool newA = (pg == 2) && hasNext;
        if (hasNext) loadB(ps + 1);
        if (newA) loadA(ps / 3 + 1);

        const char* Bs = smem + AB + (ps & 1) * PB;
        #pragma unroll
        for (int kw = 0; kw < 3; ++kw) {
            short8 a[4];
            #pragma unroll
            for (int mf = 0; mf < 4; ++mf) {
                int pos = (2 * mw + pg) * 130 + 2 * (mf * 16 + lr) + kw;
                a[mf] = *(const short8*)(As + swz(pos * 64 + kg * 16));
            }
            #pragma unroll
            for (int nf = 0; nf < 4; ++nf) {
                int rb = kw * 128 + ch * 64 + nf * 16 + lr;
                short8 b = *(const short8*)(Bs + swz(rb * 64 + kg * 16));
                #pragma unroll
                for (int mf = 0; mf < 4; ++mf)
                    acc[mf][nf] = __builtin_amdgcn_mfma_f32_16x16x32_bf16(
                        a[mf], b, acc[mf][nf], 0, 0, 0);
            }
        }

        __syncthreads();
        if (hasNext) writeB(ps + 1);
        if (newA) writeA();
        if (hasNext) __syncthreads();
    }

    const float* bs = bs0 + l * 128;
    const float* bb = bb0 + l * 128;
    const float* bm = bm0 + l * 128;
    const float* bv = bv0 + l * 128;
    ushort* ob = out + (size_t)slot * 3072 * 128;
    const int orow = r0 + mw;
    #pragma unroll
    for (int nf = 0; nf < 4; ++nf) {
        const int col = ch * 64 + nf * 16 + lr;
        const float inv = bs[col] * rsqrtf(bv[col] + EPSF);
        const float beta = bb[col] - bm[col] * inv;
        #pragma unroll
        for (int mf = 0; mf < 4; ++mf) {
            #pragma unroll
            for (int j = 0; j < 4; ++j) {
                int ocol = mf * 16 + kg * 4 + j;
                float y = fmaxf(fmaf(acc[mf][nf][j], inv, beta), 0.f);
                ob[((size_t)orow * 64 + ocol) * 128 + col] = f2bf(y);
            }
        }
    }
}

// ---------------- MFMA convT4x4 s2 (+BN+ReLU), weights via LDS -------------
__global__ __launch_bounds__(256) void k_convt_mfma(
    const ushort* __restrict__ in, ushort* __restrict__ out,
    const ushort* __restrict__ wbase,
    const float* __restrict__ bs0, const float* __restrict__ bb0,
    const float* __restrict__ bm0, const float* __restrict__ bv0, int d0)
{
    constexpr int SLICE = 4 * 32 * 128;
    constexpr int S = 4;
    __shared__ __align__(16) char smem[SLICE];

    const int tid = threadIdx.x;
    const int lane = tid & 63, wid = tid >> 6;
    const int lr = lane & 15, kg = lane >> 4;
    const int m0 = blockIdx.x * 256 + wid * 64;
    const int parity = blockIdx.y;
    const int slot = blockIdx.z;
    const int l = (d0 + slot) / 49;
    const int ph = parity >> 1, pw = parity & 1;
    const int kh0 = (ph + 1) & 1, kw0 = (pw + 1) & 1;

    {
        const char* wsrc = (const char*)(wbase + (size_t)l * (16 * 32 * 64));
        #pragma unroll
        for (int i = 0; i < S; ++i) {
            int lin = i * 4096 + tid * 16;
            int rowidx = lin >> 7;
            int tap = rowidx >> 5, r = rowidx & 31;
            short8 v = *(const short8*)(wsrc
                + (((size_t)(parity * 4 + tap) * 32 + r) * 64) * 2 + (lin & 127));
            *(short8*)(smem + swz(lin)) = v;
        }
    }
    __syncthreads();

    int ihA[4], iwA[4];
    #pragma unroll
    for (int mf = 0; mf < 4; ++mf) {
        int m = m0 + mf * 16 + lr;
        int q = m >> 6, r = m & 63;
        ihA[mf] = (2 * q + ph + 1 - kh0) >> 1;
        iwA[mf] = (2 * r + pw + 1 - kw0) >> 1;
    }
    const ushort* ib = in + (size_t)slot * 3072 * 64;

    const short8 z8 = {0, 0, 0, 0, 0, 0, 0, 0};
    f32x4 acc[4][2];
    #pragma unroll
    for (int mf = 0; mf < 4; ++mf)
        #pragma unroll
        for (int nf = 0; nf < 2; ++nf)
            acc[mf][nf] = (f32x4){0.f, 0.f, 0.f, 0.f};

    #pragma unroll
    for (int a = 0; a < 2; ++a) {
        #pragma unroll
        for (int b2 = 0; b2 < 2; ++b2) {
            int srcoff[4]; bool val[4];
            #pragma unroll
            for (int mf = 0; mf < 4; ++mf) {
                int ih = ihA[mf] - a;
                int iw = iwA[mf] - b2;
                val[mf] = ((unsigned)ih < 48u) && ((unsigned)iw < 64u);
                int ihc = min(max(ih, 0), 47), iwc = min(max(iw, 0), 63);
                srcoff[mf] = (ihc * 64 + iwc) * 64;
            }
            const int tap = a * 2 + b2;
            #pragma unroll
            for (int cc = 0; cc < 2; ++cc) {
                const int kbase = cc * 32 + kg * 8;
                short8 av[4];
                #pragma unroll
                for (int mf = 0; mf < 4; ++mf) {
                    short8 v = *(const short8*)(ib + srcoff[mf] + kbase);
                    av[mf] = val[mf] ? v : z8;
                }
                #pragma unroll
                for (int nf = 0; nf < 2; ++nf) {
                    short8 bfr = *(const short8*)(smem
                        + swz((tap * 32 + nf * 16 + lr) * 128 + cc * 64 + kg * 16));
                    #pragma unroll
                    for (int mf = 0; mf < 4; ++mf)
                        acc[mf][nf] = __builtin_amdgcn_mfma_f32_16x16x32_bf16(
                            av[mf], bfr, acc[mf][nf], 0, 0, 0);
                }
            }
        }
    }

    const float* bs = bs0 + l * 32;
    const float* bb = bb0 + l * 32;
    const float* bm = bm0 + l * 32;
    const float* bv = bv0 + l * 32;
    ushort* ob = out + (size_t)slot * 12288 * 32;
    #pragma unroll
    for (int nf = 0; nf < 2; ++nf) {
        const int col = nf * 16 + lr;
        const float inv = bs[col] * rsqrtf(bv[col] + EPSF);
        const float beta = bb[col] - bm[col] * inv;
        #pragma unroll
        for (int mf = 0; mf < 4; ++mf) {
            #pragma unroll
            for (int j = 0; j < 4; ++j) {
                int m = m0 + mf * 16 + kg * 4 + j;
                int q = m >> 6, r = m & 63;
                int sp = (2 * q + ph) * 128 + (2 * r + pw);
                float y = fmaxf(fmaf(acc[mf][nf][j], inv, beta), 0.f);
                ob[(size_t)sp * 32 + col] = f2bf(y);
            }
        }
    }
}

// ---------------- conv6 (32->1) + bias, fp32 out ---------------------------
__global__ __launch_bounds__(256) void k_conv6(
    const ushort* __restrict__ x5, float* __restrict__ cost,
    const float* __restrict__ w0, const float* __restrict__ cb6, int d0)
{
    const int sp = blockIdx.x * 256 + threadIdx.x;
    const int slot = blockIdx.z;
    const int p = d0 + slot;
    const int l = p / 49;
    const float* w = w0 + l * 288;
    const int oh = sp >> 7, ow = sp & 127;
    float acc = 0.f;
    #pragma unroll
    for (int kh = 0; kh < 3; ++kh) {
        const int ih = oh - 1 + kh;
        if (ih < 0 || ih >= 96) continue;
        #pragma unroll
        for (int kw = 0; kw < 3; ++kw) {
            const int iw = ow - 1 + kw;
            if (iw < 0 || iw >= 128) continue;
            const ushort* q = x5 + ((size_t)slot * 12288 + ih * 128 + iw) * 32;
            const int tap = kh * 3 + kw;
            #pragma unroll
            for (int g = 0; g < 4; ++g) {
                uint4 v = *(const uint4*)(q + g * 8);
                const uint* vw = (const uint*)&v;
                #pragma unroll
                for (int t = 0; t < 4; ++t) {
                    int ci = g * 8 + t * 2;
                    acc = fmaf(bf2f((ushort)(vw[t] & 0xFFFF)), w[ci * 9 + tap], acc);
                    acc = fmaf(bf2f((ushort)(vw[t] >> 16)), w[(ci + 1) * 9 + tap], acc);
                }
            }
        }
    }
    cost[(size_t)p * 12288 + sp] = acc + cb6[l];
}

// ---------------- DAP ------------------------------------------------------
__global__ __launch_bounds__(256) void k_dap(
    const float* __restrict__ cost, const float* __restrict__ dw,
    float* __restrict__ out)
{
    const int sp = blockIdx.x * 256 + threadIdx.x;
    const int p = blockIdx.y;
    const float* dr = dw + p * 49;
    float acc = 0.f;
    #pragma unroll
    for (int q = 0; q < 49; ++q)
        acc = fmaf(dr[q], cost[(size_t)q * 12288 + sp], acc);
    out[(size_t)p * 12288 + sp] = acc;
}

// ---------------------------------------------------------------------------
extern "C" void kernel_launch(void* const* d_in, const int* in_sizes, int n_in,
                              void* d_out, int out_size, void* d_ws, size_t ws_size,
                              hipStream_t stream)
{
    const float* fm1_0 = (const float*)d_in[0];
    const float* fm2_0 = (const float*)d_in[1];
    const float* fm1_1 = (const float*)d_in[2];
    const float* fm2_1 = (const float*)d_in[3];
    const float* coords = (const float*)d_in[4];
    const float* cw1  = (const float*)d_in[5];
    const float* cw2  = (const float*)d_in[6];
    const float* cw3  = (const float*)d_in[7];
    const float* cw4  = (const float*)d_in[8];
    const float* ctw5 = (const float*)d_in[9];
    const float* cw6  = (const float*)d_in[10];
    const float* cb6  = (const float*)d_in[11];
    const float* bn[5][4];
    for (int j = 0; j < 5; ++j)
        for (int k = 0; k < 4; ++k)
            bn[j][k] = (const float*)d_in[12 + j * 4 + k];
    const float* dap = (const float*)d_in[32];
    float* out = (float*)d_out;

    // ---- workspace: bufA | bufB | grouped weights | cost ----
    const size_t A_US = 786432;    // per-slot: max(x0, x2, x4)
    const size_t B_US = 1179648;   // per-slot: max(x1, x3, x5)
    const size_t W1 = 9 * 96 * 64, W2 = 9 * 128 * 96, W3 = 9 * 128 * 128;
    const size_t W4 = 9 * 64 * 128, W5 = 16 * 32 * 64;
    const size_t W_US = 2 * (W1 + W2 + W3 + W4 + W5);
    const size_t COSTF = (size_t)98 * 12288;

    int DC = 1;
    for (int cand : {98, 66, 49, 42, 33, 25, 17, 13, 9, 7, 5, 3, 2, 1}) {
        size_t need = (A_US + B_US) * (size_t)cand * 2 + W_US * 2 + COSTF * 4 + 4096;
        if (need <= ws_size) { DC = cand; break; }
    }

    ushort* bufA = (ushort*)d_ws;
    ushort* bufB = bufA + A_US * DC;
    ushort* wp = bufB + B_US * DC;
    ushort* wr1 = wp; wp += 2 * W1;
    ushort* wr2 = wp; wp += 2 * W2;
    ushort* wr3 = wp; wp += 2 * W3;
    ushort* wr4 = wp; wp += 2 * W4;
    ushort* wr5 = wp; wp += 2 * W5;
    float* cost = (float*)wp;

    for (int l = 0; l < 2; ++l) {
        k_repack_conv<<<dim3(216), 256, 0, stream>>>(cw1 + (size_t)l * W1, wr1 + l * W1, 96, 64);
        k_repack_conv<<<dim3(432), 256, 0, stream>>>(cw2 + (size_t)l * W2, wr2 + l * W2, 128, 96);
        k_repack_conv<<<dim3(576), 256, 0, stream>>>(cw3 + (size_t)l * W3, wr3 + l * W3, 128, 128);
        k_repack_conv<<<dim3(288), 256, 0, stream>>>(cw4 + (size_t)l * W4, wr4 + l * W4, 64, 128);
        k_repack_ct<<<dim3(128), 256, 0, stream>>>(ctw5 + (size_t)l * W5, wr5 + l * W5);
    }

    for (int d0 = 0; d0 < 98; d0 += DC) {
        const int ndd = min(DC, 98 - d0);
        k_sample_nhwc<<<dim3(48, 1, ndd), 256, 0, stream>>>(
            fm1_0, fm1_1, fm2_0, fm2_1, coords, bufA, d0);
        k_conv_lds8<64, 96, 96, 96, 128>
            <<<dim3(24, 1, ndd), 512, 0, stream>>>(bufA, bufB, wr1, (int)W1,
                bn[0][0], bn[0][1], bn[0][2], bn[0][3], d0);
        k_conv_s2_8<<<dim3(12, 1, ndd), 512, 0, stream>>>(bufB, bufA, wr2, (int)W2,
                bn[1][0], bn[1][1], bn[1][2], bn[1][3], d0);
        k_conv_lds8<128, 128, 64, 48, 64>
            <<<dim3(6, 2, ndd), 512, 0, stream>>>(bufA, bufB, wr3, (int)W3,
                bn[2][0], bn[2][1], bn[2][2], bn[2][3], d0);
        k_conv_lds8<128, 64, 64, 48, 64>
            <<<dim3(6, 1, ndd), 512, 0, stream>>>(bufB, bufA, wr4, (int)W4,
                bn[3][0], bn[3][1], bn[3][2], bn[3][3], d0);
        k_convt_mfma<<<dim3(12, 4, ndd), 256, 0, stream>>>(bufA, bufB, wr5,
                bn[4][0], bn[4][1], bn[4][2], bn[4][3], d0);
        k_conv6<<<dim3(48, 1, ndd), 256, 0, stream>>>(
            bufB, cost, cw6, cb6, d0);
    }
    for (int l = 0; l < 2; ++l)
        k_dap<<<dim3(48, 49), 256, 0, stream>>>(
            cost + (size_t)l * 49 * 12288, dap + (size_t)l * 49 * 49,
            out + (size_t)l * 49 * 12288);
}